// Round 6
// baseline (407.847 us; speedup 1.0000x reference)
//
#include <hip/hip_runtime.h>
#include <hip/hip_bf16.h>

typedef unsigned short u16;
typedef unsigned int u32;
typedef short short8 __attribute__((ext_vector_type(8)));
typedef unsigned short ushort4v __attribute__((ext_vector_type(4)));
typedef float f32x4 __attribute__((ext_vector_type(4)));
typedef float f32x16 __attribute__((ext_vector_type(16)));
typedef u32 u32x4 __attribute__((ext_vector_type(4)));

#define SEQN 4096
#define HID 2048
#define NH 16
#define NKV 4
#define HD 128
#define QDIM 2048   // NH*HD
#define KVD 512     // NKV*HD

static __device__ __forceinline__ float bf2f(u16 u){
  unsigned x = ((unsigned)u) << 16; float f; __builtin_memcpy(&f, &x, 4); return f;
}
static __device__ __forceinline__ u16 f2bf(float f){
  unsigned x; __builtin_memcpy(&x, &f, 4);
  x += 0x7fffu + ((x >> 16) & 1u);
  return (u16)(x >> 16);
}
static __device__ __forceinline__ u32 pk2(float a, float b){
  return (u32)f2bf(a) | ((u32)f2bf(b) << 16);
}

// ---------------- fp32 -> bf16 convert ----------------
__global__ __launch_bounds__(256) void cvt_kernel(const float* __restrict__ in, u16* __restrict__ out, int n4){
  int i = blockIdx.x * 256 + threadIdx.x;
  if (i >= n4) return;
  f32x4 v = ((const f32x4*)in)[i];
  ushort4v o;
  o.x = f2bf(v.x); o.y = f2bf(v.y); o.z = f2bf(v.z); o.w = f2bf(v.w);
  ((ushort4v*)out)[i] = o;
}

// ---------------- RoPE (in-place on bf16) ----------------
__global__ __launch_bounds__(256) void rope_kernel(u16* __restrict__ X, int nheads, int total){
  int idx = blockIdx.x * 256 + threadIdx.x;
  if (idx >= total) return;
  int i = idx & 63;          // pair index 0..63
  int rest = idx >> 6;
  int h = rest % nheads;
  int s = rest / nheads;
  float freq = expf(-0.14391156831212788f * (float)i);
  float ang = (float)s * freq;
  float c = cosf(ang), sn = sinf(ang);
  u16* p = X + (size_t)s * ((size_t)nheads * HD) + (size_t)h * HD + 2 * i;
  float x1 = bf2f(p[0]), x2 = bf2f(p[1]);
  p[0] = f2bf(x1 * c - x2 * sn);
  p[1] = f2bf(x1 * sn + x2 * c);
}

// ---------------- async global->LDS 16B ----------------
static __device__ __forceinline__ void gload16(const void* g, void* l){
  __builtin_amdgcn_global_load_lds((const __attribute__((address_space(1))) void*)g,
                                   (__attribute__((address_space(3))) void*)l, 16, 0, 0);
}

// ---------------- GEMM: C[M][N] = A[M][K] * B[N][K]^T ----------------
template<int F32OUT>
__global__ __launch_bounds__(256) void gemm_kernel(const u16* __restrict__ A, const u16* __restrict__ B,
                                                   void* __restrict__ Cout, int M, int N, int Kd){
  __shared__ alignas(16) u16 As[128 * 32];
  __shared__ alignas(16) u16 Bs[128 * 32];
  const int tid = threadIdx.x;
  const int w = tid >> 6, l = tid & 63;
  const int wr = w >> 1, wc = w & 1;
  const int lc = l & 15, lg = l >> 4;
  const int tm = blockIdx.x * 128, tn = blockIdx.y * 128;

  const int srow = w * 32 + (l >> 2);
  const int scol = (l & 3) * 8;
  const u16* Ag = A + (size_t)(tm + srow) * Kd + scol;
  const u16* Bg = B + (size_t)(tn + srow) * Kd + scol;
  u16* As0 = As + (w * 2) * 512;
  u16* Bs0 = Bs + (w * 2) * 512;

  f32x4 acc[4][4] = {};

  for (int k0 = 0; k0 < Kd; k0 += 32){
    gload16(Ag + k0,                    As0);
    gload16(Ag + k0 + (size_t)16 * Kd,  As0 + 512);
    gload16(Bg + k0,                    Bs0);
    gload16(Bg + k0 + (size_t)16 * Kd,  Bs0 + 512);
    __syncthreads();
    short8 a[4], b[4];
#pragma unroll
    for (int mi = 0; mi < 4; mi++) a[mi] = *(const short8*)&As[(wr*64 + mi*16 + lc) * 32 + lg*8];
#pragma unroll
    for (int ni = 0; ni < 4; ni++) b[ni] = *(const short8*)&Bs[(wc*64 + ni*16 + lc) * 32 + lg*8];
#pragma unroll
    for (int mi = 0; mi < 4; mi++)
#pragma unroll
      for (int ni = 0; ni < 4; ni++)
        acc[mi][ni] = __builtin_amdgcn_mfma_f32_16x16x32_bf16(a[mi], b[ni], acc[mi][ni], 0, 0, 0);
    __syncthreads();
  }

#pragma unroll
  for (int mi = 0; mi < 4; mi++)
#pragma unroll
    for (int ni = 0; ni < 4; ni++)
#pragma unroll
      for (int r = 0; r < 4; r++){
        int row = tm + wr*64 + mi*16 + lg*4 + r;
        int col = tn + wc*64 + ni*16 + lc;
        float v = acc[mi][ni][r];
        if (F32OUT) ((float*)Cout)[(size_t)row * N + col] = v;
        else        ((u16*)Cout)[(size_t)row * N + col] = f2bf(v);
      }
}

// ---------------- Flash attention (causal, GQA), 32x32 MFMA, swapped ops ----------------
// Grid (16, NH, 2): block (x,h,z) handles qt = z ? 31-x : x. Blocks c and c+256 land on
// the same CU with complementary work (light+heavy) -> 2 blocks/CU, uniform 68 tiles/CU,
// cross-block stall hiding. 4 waves x 32 q-rows. KV tile 64, reg-staged with prefetch.
// K in LDS [64][136] natural. V transposed into [128][72] (chunk-XOR swizzle).
// Swapped QK^T -> S^T[kv][q]; softmax fully per-lane (+1 cross-half shfl).
// P stays IN REGISTERS: bf16-packed Sv pairs exchanged across lane halves via
// shfl_xor(32) + selects (no P LDS traffic). Swapped PV -> O^T[d][q].
// Epilogue transposes via per-wave LDS reuse.
__global__ __launch_bounds__(256) void attn_kernel(const u16* __restrict__ Q, const u16* __restrict__ K,
                                                   const u16* __restrict__ V, u16* __restrict__ Aout){
  __shared__ alignas(16) char pool[35840];
  u16 (*Ks)[136] = (u16(*)[136])pool;                  // 64*136*2  = 17408 B
  u16 (*VT)[72]  = (u16(*)[72])(pool + 17408);         // 128*72*2  = 18432 B

  const int pr  = blockIdx.x;            // 0..15
  const int h   = blockIdx.y;
  const int kvh = h >> 2;
  const int tid = threadIdx.x;
  const int w = tid >> 6, l = tid & 63;
  const int q5 = l & 31;
  const int hi = l >> 5;
  const int hi4 = hi * 4;
  const float csc = 0.12751743f;         // (1/sqrt(128)) * log2(e)

  const int krow = tid >> 4;      // 0..15
  const int kch  = tid & 15;
  const int vrow = tid & 63;
  const int vc0  = (tid >> 6) * 8;

  const int qt    = blockIdx.z ? (31 - pr) : pr;
  const int qbase = qt * 128 + w * 32;
  const int qa    = qbase + q5;
  const int ntiles = 2 * qt + 2;

  // Q fragments (B operand): col = l&31 = q, k = hi*8 + j
  short8 qf[8];
  {
    const u16* qp = Q + (size_t)(qbase + q5) * QDIM + h * HD + hi * 8;
#pragma unroll
    for (int k0 = 0; k0 < 8; k0++) qf[k0] = *(const short8*)(qp + k0 * 16);
  }

  f32x16 Ov[4] = {};      // O^T: d = nbd*32 + rowmap(r,hi), q = q5
  float Lrow = 0.f;
  float ms = -1e30f;

  // ---- prefetch tile 0 into regs ----
  short8 kr[4], vr[4];
#pragma unroll
  for (int it = 0; it < 4; it++)
    kr[it] = *(const short8*)(K + (size_t)(it * 16 + krow) * KVD + kvh * HD + kch * 8);
#pragma unroll
  for (int it = 0; it < 4; it++)
    vr[it] = *(const short8*)(V + (size_t)vrow * KVD + kvh * HD + vc0 + it * 32);

  for (int t = 0; t < ntiles; t++){
    const int kv0 = t * 64;

    __syncthreads();    // previous tile's compute done

    // ---- write staged K regs -> LDS (natural layout) ----
#pragma unroll
    for (int it = 0; it < 4; it++)
      *(short8*)&Ks[it * 16 + krow][kch * 8] = kr[it];
    // ---- write staged V regs -> LDS transposed (scalar, chunk-XOR swizzle) ----
#pragma unroll
    for (int it = 0; it < 4; it++){
      int cc = vc0 + it * 32;
#pragma unroll
      for (int j = 0; j < 8; j++){
        int d = cc + j;
        int chunk = (vrow >> 3) ^ ((d >> 3) & 3);
        VT[d][chunk * 8 + (vrow & 7)] = (u16)vr[it][j];
      }
    }
    // ---- issue next tile's global loads (hide latency under compute) ----
    if (t + 1 < ntiles){
      const int nkv = kv0 + 64;
#pragma unroll
      for (int it = 0; it < 4; it++)
        kr[it] = *(const short8*)(K + (size_t)(nkv + it * 16 + krow) * KVD + kvh * HD + kch * 8);
#pragma unroll
      for (int it = 0; it < 4; it++)
        vr[it] = *(const short8*)(V + (size_t)(nkv + vrow) * KVD + kvh * HD + vc0 + it * 32);
    }
    __syncthreads();    // LDS tile ready

    if (kv0 <= qbase + 31){
      // ---- QK^T swapped: S^T[kv][q] ----
      f32x16 Sv[2] = {};
#pragma unroll
      for (int k0 = 0; k0 < 8; k0++){
#pragma unroll
        for (int nb = 0; nb < 2; nb++){
          int kvr = nb * 32 + q5;
          short8 kf = *(const short8*)&Ks[kvr][(k0 * 2 + hi) * 8];
          Sv[nb] = __builtin_amdgcn_mfma_f32_32x32x16_bf16(kf, qf[k0], Sv[nb], 0, 0, 0);
        }
      }
      // ---- causal mask (raw scores) ----
      if (kv0 + 63 > qbase){
#pragma unroll
        for (int nb = 0; nb < 2; nb++)
#pragma unroll
          for (int r = 0; r < 16; r++){
            int kva = kv0 + nb * 32 + (r & 3) + 8 * (r >> 2) + hi4;
            if (kva > qa) Sv[nb][r] = -1e30f;
          }
      }
      // ---- online softmax, scaled-log2 domain, defer-max THR=8 ----
      float tm = -3e38f;
#pragma unroll
      for (int nb = 0; nb < 2; nb++)
#pragma unroll
        for (int r = 0; r < 16; r++) tm = fmaxf(tm, Sv[nb][r]);
      tm = fmaxf(tm, __shfl_xor(tm, 32));
      float tms = tm * csc;
      if (!__all(tms - ms <= 8.f)){
        float nms = fmaxf(ms, tms);
        float al = __builtin_amdgcn_exp2f(ms - nms);
        ms = nms;
        Lrow *= al;
#pragma unroll
        for (int nb = 0; nb < 4; nb++)
#pragma unroll
          for (int r = 0; r < 16; r++) Ov[nb][r] *= al;
      }
      float ts = 0.f;
#pragma unroll
      for (int nb = 0; nb < 2; nb++)
#pragma unroll
        for (int r = 0; r < 16; r++){
          float p = __builtin_amdgcn_exp2f(__builtin_fmaf(Sv[nb][r], csc, -ms));
          Sv[nb][r] = p;
          ts += p;
        }
      ts += __shfl_xor(ts, 32);
      Lrow += ts;
      // ---- P in registers: pack bf16 pairs, exchange halves via shfl_xor(32) ----
      // dest half hi=0 words {A,B,sA,sB}; hi=1 words {sC,sD,C,D}  (verified mapping)
#pragma unroll
      for (int kc = 0; kc < 4; kc++){
        const int nb = kc >> 1, rb = (kc & 1) * 8;
        u32 Aw = pk2(Sv[nb][rb + 0], Sv[nb][rb + 1]);
        u32 Bw = pk2(Sv[nb][rb + 2], Sv[nb][rb + 3]);
        u32 Cw = pk2(Sv[nb][rb + 4], Sv[nb][rb + 5]);
        u32 Dw = pk2(Sv[nb][rb + 6], Sv[nb][rb + 7]);
        u32 sAw = __shfl_xor(Aw, 32);
        u32 sBw = __shfl_xor(Bw, 32);
        u32 sCw = __shfl_xor(Cw, 32);
        u32 sDw = __shfl_xor(Dw, 32);
        u32 w0 = hi ? sCw : Aw;
        u32 w1 = hi ? sDw : Bw;
        u32 w2 = hi ? Cw : sAw;
        u32 w3 = hi ? Dw : sBw;
        u32x4 pw4 = {w0, w1, w2, w3};
        short8 pf = *(short8*)&pw4;
        // ---- PV swapped: O^T[d][q] += V^T * P^T ----
#pragma unroll
        for (int nbd = 0; nbd < 4; nbd++){
          int drow = nbd * 32 + q5;
          short8 vf = *(const short8*)&VT[drow][((kc * 2 + hi) ^ ((drow >> 3) & 3)) * 8];
          Ov[nbd] = __builtin_amdgcn_mfma_f32_32x32x16_bf16(vf, pf, Ov[nbd], 0, 0, 0);
        }
      }
    }
  }

  __syncthreads();    // all waves done computing before epilogue overwrites pool

  // ---- epilogue: normalize, transpose via per-wave LDS reuse, coalesced store ----
  u16* Ew = (u16*)(pool + w * 8704);     // [32 q][136 d] u16
  float rl = 1.f / Lrow;
#pragma unroll
  for (int nbd = 0; nbd < 4; nbd++)
#pragma unroll
    for (int r = 0; r < 16; r += 2){
      int d = nbd * 32 + (r & 3) + 8 * (r >> 2) + hi4;       // even
      u32 wpk = pk2(Ov[nbd][r] * rl, Ov[nbd][r + 1] * rl);
      *(u32*)((char*)Ew + q5 * 272 + d * 2) = wpk;
    }
#pragma unroll
  for (int pass = 0; pass < 8; pass++){
    int q2 = pass * 4 + (l >> 4);
    short8 ov = *(const short8*)((char*)Ew + q2 * 272 + (l & 15) * 16);
    *(short8*)(Aout + (size_t)(qbase + q2) * QDIM + h * HD + (l & 15) * 8) = ov;
  }
}

extern "C" void kernel_launch(void* const* d_in, const int* in_sizes, int n_in,
                              void* d_out, int out_size, void* d_ws, size_t ws_size,
                              hipStream_t stream){
  const float* x  = (const float*)d_in[0];
  const float* Wq = (const float*)d_in[1];
  const float* Wk = (const float*)d_in[2];
  const float* Wv = (const float*)d_in[3];
  const float* Wo = (const float*)d_in[4];

  char* p = (char*)d_ws;
  u16* xb  = (u16*)p; p += (size_t)SEQN * HID * 2;
  u16* Wqb = (u16*)p; p += (size_t)QDIM * HID * 2;
  u16* Wkb = (u16*)p; p += (size_t)KVD * HID * 2;
  u16* Wvb = (u16*)p; p += (size_t)KVD * HID * 2;
  u16* Wob = (u16*)p; p += (size_t)HID * QDIM * 2;
  u16* Qb  = (u16*)p; p += (size_t)SEQN * QDIM * 2;
  u16* Kb  = (u16*)p; p += (size_t)SEQN * KVD * 2;
  u16* Vb  = (u16*)p; p += (size_t)SEQN * KVD * 2;
  u16* Ab  = (u16*)p; p += (size_t)SEQN * QDIM * 2;

  cvt_kernel<<<(SEQN*HID/4 + 255)/256, 256, 0, stream>>>(x,  xb,  SEQN*HID/4);
  cvt_kernel<<<(QDIM*HID/4 + 255)/256, 256, 0, stream>>>(Wq, Wqb, QDIM*HID/4);
  cvt_kernel<<<(KVD*HID/4 + 255)/256, 256, 0, stream>>>(Wk, Wkb, KVD*HID/4);
  cvt_kernel<<<(KVD*HID/4 + 255)/256, 256, 0, stream>>>(Wv, Wvb, KVD*HID/4);
  cvt_kernel<<<(HID*QDIM/4 + 255)/256, 256, 0, stream>>>(Wo, Wob, HID*QDIM/4);

  gemm_kernel<0><<<dim3(SEQN/128, QDIM/128), 256, 0, stream>>>(xb, Wqb, Qb, SEQN, QDIM, HID);
  gemm_kernel<0><<<dim3(SEQN/128, KVD/128),  256, 0, stream>>>(xb, Wkb, Kb, SEQN, KVD, HID);
  gemm_kernel<0><<<dim3(SEQN/128, KVD/128),  256, 0, stream>>>(xb, Wvb, Vb, SEQN, KVD, HID);

  rope_kernel<<<(SEQN*NH*64)/256,  256, 0, stream>>>(Qb, NH,  SEQN*NH*64);
  rope_kernel<<<(SEQN*NKV*64)/256, 256, 0, stream>>>(Kb, NKV, SEQN*NKV*64);

  attn_kernel<<<dim3(16, NH, 2), 256, 0, stream>>>(Qb, Kb, Vb, Ab);

  gemm_kernel<1><<<dim3(SEQN/128, HID/128), 256, 0, stream>>>(Ab, Wob, d_out, SEQN, HID, QDIM);
}

// Round 7
// 369.979 us; speedup vs baseline: 1.1024x; 1.1024x over previous
//
#include <hip/hip_runtime.h>
#include <hip/hip_bf16.h>

typedef unsigned short u16;
typedef unsigned int u32;
typedef short short8 __attribute__((ext_vector_type(8)));
typedef unsigned short ushort4v __attribute__((ext_vector_type(4)));
typedef float f32x4 __attribute__((ext_vector_type(4)));
typedef float f32x16 __attribute__((ext_vector_type(16)));
typedef u32 u32x4 __attribute__((ext_vector_type(4)));

#define SEQN 4096
#define HID 2048
#define NH 16
#define NKV 4
#define HD 128
#define QDIM 2048   // NH*HD
#define KVD 512     // NKV*HD

static __device__ __forceinline__ float bf2f(u16 u){
  unsigned x = ((unsigned)u) << 16; float f; __builtin_memcpy(&f, &x, 4); return f;
}
static __device__ __forceinline__ u16 f2bf(float f){
  unsigned x; __builtin_memcpy(&x, &f, 4);
  x += 0x7fffu + ((x >> 16) & 1u);
  return (u16)(x >> 16);
}
static __device__ __forceinline__ u32 pk2(float a, float b){
  return (u32)f2bf(a) | ((u32)f2bf(b) << 16);
}

// ---------------- fp32 -> bf16 convert ----------------
__global__ __launch_bounds__(256) void cvt_kernel(const float* __restrict__ in, u16* __restrict__ out, int n4){
  int i = blockIdx.x * 256 + threadIdx.x;
  if (i >= n4) return;
  f32x4 v = ((const f32x4*)in)[i];
  ushort4v o;
  o.x = f2bf(v.x); o.y = f2bf(v.y); o.z = f2bf(v.z); o.w = f2bf(v.w);
  ((ushort4v*)out)[i] = o;
}

// ---------------- RoPE (in-place on bf16) ----------------
__global__ __launch_bounds__(256) void rope_kernel(u16* __restrict__ X, int nheads, int total){
  int idx = blockIdx.x * 256 + threadIdx.x;
  if (idx >= total) return;
  int i = idx & 63;          // pair index 0..63
  int rest = idx >> 6;
  int h = rest % nheads;
  int s = rest / nheads;
  float freq = expf(-0.14391156831212788f * (float)i);
  float ang = (float)s * freq;
  float c = cosf(ang), sn = sinf(ang);
  u16* p = X + (size_t)s * ((size_t)nheads * HD) + (size_t)h * HD + 2 * i;
  float x1 = bf2f(p[0]), x2 = bf2f(p[1]);
  p[0] = f2bf(x1 * c - x2 * sn);
  p[1] = f2bf(x1 * sn + x2 * c);
}

// ---------------- V transpose: V[s][c] -> VTg[c][s]  (c = kvh*128+d) ----------------
__global__ __launch_bounds__(256) void vtrans_kernel(const u16* __restrict__ V, u16* __restrict__ VTg){
  __shared__ u16 T[64][72];
  const int s0 = blockIdx.x * 64;
  const int c0 = blockIdx.y * 64;
  const int tid = threadIdx.x;
  const int sl = tid & 63, ch = tid >> 6;   // ch 0..3
  const u16* src = V + (size_t)(s0 + sl) * KVD + c0 + ch * 16;
  *(short8*)&T[sl][ch * 16]     = *(const short8*)(src);
  *(short8*)&T[sl][ch * 16 + 8] = *(const short8*)(src + 8);
  __syncthreads();
#pragma unroll
  for (int it = 0; it < 16; it++){
    int c = it * 4 + ch;
    VTg[(size_t)(c0 + c) * SEQN + s0 + sl] = T[sl][c];
  }
}

// ---------------- async global->LDS 16B ----------------
static __device__ __forceinline__ void gload16(const void* g, void* l){
  __builtin_amdgcn_global_load_lds((const __attribute__((address_space(1))) void*)g,
                                   (__attribute__((address_space(3))) void*)l, 16, 0, 0);
}

// ---------------- GEMM: C[M][N] = A[M][K] * B[N][K]^T ----------------
template<int F32OUT>
__global__ __launch_bounds__(256) void gemm_kernel(const u16* __restrict__ A, const u16* __restrict__ B,
                                                   void* __restrict__ Cout, int M, int N, int Kd){
  __shared__ alignas(16) u16 As[128 * 32];
  __shared__ alignas(16) u16 Bs[128 * 32];
  const int tid = threadIdx.x;
  const int w = tid >> 6, l = tid & 63;
  const int wr = w >> 1, wc = w & 1;
  const int lc = l & 15, lg = l >> 4;
  const int tm = blockIdx.x * 128, tn = blockIdx.y * 128;

  const int srow = w * 32 + (l >> 2);
  const int scol = (l & 3) * 8;
  const u16* Ag = A + (size_t)(tm + srow) * Kd + scol;
  const u16* Bg = B + (size_t)(tn + srow) * Kd + scol;
  u16* As0 = As + (w * 2) * 512;
  u16* Bs0 = Bs + (w * 2) * 512;

  f32x4 acc[4][4] = {};

  for (int k0 = 0; k0 < Kd; k0 += 32){
    gload16(Ag + k0,                    As0);
    gload16(Ag + k0 + (size_t)16 * Kd,  As0 + 512);
    gload16(Bg + k0,                    Bs0);
    gload16(Bg + k0 + (size_t)16 * Kd,  Bs0 + 512);
    __syncthreads();
    short8 a[4], b[4];
#pragma unroll
    for (int mi = 0; mi < 4; mi++) a[mi] = *(const short8*)&As[(wr*64 + mi*16 + lc) * 32 + lg*8];
#pragma unroll
    for (int ni = 0; ni < 4; ni++) b[ni] = *(const short8*)&Bs[(wc*64 + ni*16 + lc) * 32 + lg*8];
#pragma unroll
    for (int mi = 0; mi < 4; mi++)
#pragma unroll
      for (int ni = 0; ni < 4; ni++)
        acc[mi][ni] = __builtin_amdgcn_mfma_f32_16x16x32_bf16(a[mi], b[ni], acc[mi][ni], 0, 0, 0);
    __syncthreads();
  }

#pragma unroll
  for (int mi = 0; mi < 4; mi++)
#pragma unroll
    for (int ni = 0; ni < 4; ni++)
#pragma unroll
      for (int r = 0; r < 4; r++){
        int row = tm + wr*64 + mi*16 + lg*4 + r;
        int col = tn + wc*64 + ni*16 + lc;
        float v = acc[mi][ni][r];
        if (F32OUT) ((float*)Cout)[(size_t)row * N + col] = v;
        else        ((u16*)Cout)[(size_t)row * N + col] = f2bf(v);
      }
}

// ---------------- Flash attention (causal, GQA), 32x32 MFMA, swapped ops ----------------
// Grid (16, NH): block x handles qt=x then qt=31-x sequentially (uniform 66 tiles).
// 4 waves x 32 q-rows. KV tile 64, DOUBLE-BUFFERED LDS (1 barrier/tile), two named
// reg sets (A/B) staged 2-3 tiles ahead. K in LDS [64][128], chunk-XOR c^(row&7).
// V pre-transposed globally (VTg[d][s]); VT LDS [128][64], chunk-XOR c^(d&7).
// Swapped QK^T -> S^T[kv][q]; per-lane softmax (+1 cross-half shfl); P in registers
// via bf16 pack + shfl_xor(32) half-exchange; swapped PV -> O^T[d][q].
// Epilogue transposes via per-wave LDS reuse.
__global__ __launch_bounds__(256) void attn_kernel(const u16* __restrict__ Q, const u16* __restrict__ K,
                                                   const u16* __restrict__ VTg, u16* __restrict__ Aout){
  __shared__ alignas(16) char pool[65536];   // 2 x (Ks 16KB + VT 16KB)

  const int pr  = blockIdx.x;            // 0..15
  const int h   = blockIdx.y;
  const int kvh = h >> 2;
  const int tid = threadIdx.x;
  const int w = tid >> 6, l = tid & 63;
  const int q5 = l & 31;
  const int hi = l >> 5;
  const int hi4 = hi * 4;
  const float csc = 0.12751743f;         // (1/sqrt(128)) * log2(e)

  const int krow = tid >> 4;             // 0..15
  const int kch  = tid & 15;
  const int vd   = tid >> 1;             // 0..127
  const int vck  = (tid & 1) * 4;        // V chunk base (0 or 4)

  const u16* Kg = K + kvh * HD + kch * 8;
  const u16* Vg = VTg + (size_t)(kvh * 128 + vd) * SEQN;

  // ---- staging helpers (all statically unrolled) ----
  auto loadK = [&](short8* kr, int kv0){
#pragma unroll
    for (int it = 0; it < 4; it++)
      kr[it] = *(const short8*)(Kg + (size_t)(kv0 + it * 16 + krow) * KVD);
  };
  auto loadV = [&](short8* vr, int kv0){
#pragma unroll
    for (int c = 0; c < 4; c++)
      vr[c] = *(const short8*)(Vg + kv0 + (vck + c) * 8);
  };
  auto writeT = [&](int b, short8* kr, short8* vr){
    char* Ksb = pool + b * 32768;
    char* VTb = pool + b * 32768 + 16384;
#pragma unroll
    for (int it = 0; it < 4; it++){
      int row = it * 16 + krow;
      *(short8*)(Ksb + row * 256 + ((kch ^ (row & 7)) << 4)) = kr[it];
    }
#pragma unroll
    for (int c = 0; c < 4; c++){
      int ck = vck + c;
      *(short8*)(VTb + vd * 128 + ((ck ^ (vd & 7)) << 4)) = vr[c];
    }
  };

  for (int ph = 0; ph < 2; ph++){
    const int qt    = ph ? (31 - pr) : pr;
    const int qbase = qt * 128 + w * 32;
    const int qa    = qbase + q5;
    const int ntiles = 2 * qt + 2;       // always even

    // Q fragments (B operand): col = l&31 = q, k = hi*8 + j
    short8 qf[8];
    {
      const u16* qp = Q + (size_t)(qbase + q5) * QDIM + h * HD + hi * 8;
#pragma unroll
      for (int k0 = 0; k0 < 8; k0++) qf[k0] = *(const short8*)(qp + k0 * 16);
    }

    f32x16 Ov[4] = {};      // O^T: d = nbd*32 + rowmap(r,hi), q = q5
    float Lrow = 0.f;
    float ms = -1e30f;

    auto computeTile = [&](int b, int kv0){
      if (kv0 > qbase + 31) return;
      char* Ksb = pool + b * 32768;
      char* VTb = pool + b * 32768 + 16384;
      // ---- QK^T swapped: S^T[kv][q] ----
      f32x16 Sv[2] = {};
#pragma unroll
      for (int k0 = 0; k0 < 8; k0++){
#pragma unroll
        for (int nb = 0; nb < 2; nb++){
          int kvr = nb * 32 + q5;
          short8 kf = *(const short8*)(Ksb + kvr * 256 + (((k0 * 2 + hi) ^ (kvr & 7)) << 4));
          Sv[nb] = __builtin_amdgcn_mfma_f32_32x32x16_bf16(kf, qf[k0], Sv[nb], 0, 0, 0);
        }
      }
      // ---- causal mask (raw scores) ----
      if (kv0 + 63 > qbase){
#pragma unroll
        for (int nb = 0; nb < 2; nb++)
#pragma unroll
          for (int r = 0; r < 16; r++){
            int kva = kv0 + nb * 32 + (r & 3) + 8 * (r >> 2) + hi4;
            if (kva > qa) Sv[nb][r] = -1e30f;
          }
      }
      // ---- online softmax, scaled-log2 domain, defer-max THR=8 ----
      float tm = -3e38f;
#pragma unroll
      for (int nb = 0; nb < 2; nb++)
#pragma unroll
        for (int r = 0; r < 16; r++) tm = fmaxf(tm, Sv[nb][r]);
      tm = fmaxf(tm, __shfl_xor(tm, 32));
      float tms = tm * csc;
      if (!__all(tms - ms <= 8.f)){
        float nms = fmaxf(ms, tms);
        float al = __builtin_amdgcn_exp2f(ms - nms);
        ms = nms;
        Lrow *= al;
#pragma unroll
        for (int nb = 0; nb < 4; nb++)
#pragma unroll
          for (int r = 0; r < 16; r++) Ov[nb][r] *= al;
      }
      float ts = 0.f;
#pragma unroll
      for (int nb = 0; nb < 2; nb++)
#pragma unroll
        for (int r = 0; r < 16; r++){
          float p = __builtin_amdgcn_exp2f(__builtin_fmaf(Sv[nb][r], csc, -ms));
          Sv[nb][r] = p;
          ts += p;
        }
      ts += __shfl_xor(ts, 32);
      Lrow += ts;
      // ---- P in registers: pack bf16 pairs, exchange halves via shfl_xor(32) ----
#pragma unroll
      for (int kc = 0; kc < 4; kc++){
        const int nb = kc >> 1, rb = (kc & 1) * 8;
        u32 Aw = pk2(Sv[nb][rb + 0], Sv[nb][rb + 1]);
        u32 Bw = pk2(Sv[nb][rb + 2], Sv[nb][rb + 3]);
        u32 Cw = pk2(Sv[nb][rb + 4], Sv[nb][rb + 5]);
        u32 Dw = pk2(Sv[nb][rb + 6], Sv[nb][rb + 7]);
        u32 sAw = __shfl_xor(Aw, 32);
        u32 sBw = __shfl_xor(Bw, 32);
        u32 sCw = __shfl_xor(Cw, 32);
        u32 sDw = __shfl_xor(Dw, 32);
        u32 w0 = hi ? sCw : Aw;
        u32 w1 = hi ? sDw : Bw;
        u32 w2 = hi ? Cw : sAw;
        u32 w3 = hi ? Dw : sBw;
        u32x4 pw4 = {w0, w1, w2, w3};
        short8 pf = *(short8*)&pw4;
        // ---- PV swapped: O^T[d][q] += V^T * P^T ----
#pragma unroll
        for (int nbd = 0; nbd < 4; nbd++){
          int drow = nbd * 32 + q5;
          short8 vf = *(const short8*)(VTb + drow * 128 + (((kc * 2 + hi) ^ (drow & 7)) << 4));
          Ov[nbd] = __builtin_amdgcn_mfma_f32_32x32x16_bf16(vf, pf, Ov[nbd], 0, 0, 0);
        }
      }
    };

    // ---- double-buffered main loop, pair-unrolled, 1 barrier per tile ----
    short8 krA[4], vrA[4], krB[4], vrB[4];
    loadK(krA, 0); loadV(vrA, 0);
    __syncthreads();                       // prior phase epilogue reads done
    writeT(0, krA, vrA);
    if (ntiles > 1){ loadK(krA, 64); loadV(vrA, 64); }
    __syncthreads();

    for (int t = 0; t < ntiles; t += 2){
      // LDS[0] = tile t; regsA = tile t+1
      if (t + 2 < ntiles){ loadK(krB, (t + 2) * 64); loadV(vrB, (t + 2) * 64); }
      computeTile(0, t * 64);
      writeT(1, krA, vrA);                 // tile t+1
      __syncthreads();
      if (t + 3 < ntiles){ loadK(krA, (t + 3) * 64); loadV(vrA, (t + 3) * 64); }
      computeTile(1, (t + 1) * 64);
      if (t + 2 < ntiles) writeT(0, krB, vrB);
      __syncthreads();
    }

    // ---- epilogue: normalize, transpose via per-wave LDS reuse, coalesced store ----
    u16* Ew = (u16*)(pool + w * 8704);     // [32 q][136 d] u16
    float rl = 1.f / Lrow;
#pragma unroll
    for (int nbd = 0; nbd < 4; nbd++)
#pragma unroll
      for (int r = 0; r < 16; r += 2){
        int d = nbd * 32 + (r & 3) + 8 * (r >> 2) + hi4;     // even
        u32 wpk = pk2(Ov[nbd][r] * rl, Ov[nbd][r + 1] * rl);
        *(u32*)((char*)Ew + q5 * 272 + d * 2) = wpk;
      }
#pragma unroll
    for (int pass = 0; pass < 8; pass++){
      int q2 = pass * 4 + (l >> 4);
      short8 ov = *(const short8*)((char*)Ew + q2 * 272 + (l & 15) * 16);
      *(short8*)(Aout + (size_t)(qbase + q2) * QDIM + h * HD + (l & 15) * 8) = ov;
    }
    // next phase's first barrier protects Ew/pool reuse
  }
}

extern "C" void kernel_launch(void* const* d_in, const int* in_sizes, int n_in,
                              void* d_out, int out_size, void* d_ws, size_t ws_size,
                              hipStream_t stream){
  const float* x  = (const float*)d_in[0];
  const float* Wq = (const float*)d_in[1];
  const float* Wk = (const float*)d_in[2];
  const float* Wv = (const float*)d_in[3];
  const float* Wo = (const float*)d_in[4];

  char* p = (char*)d_ws;
  u16* xb  = (u16*)p; p += (size_t)SEQN * HID * 2;
  u16* Wqb = (u16*)p; p += (size_t)QDIM * HID * 2;
  u16* Wkb = (u16*)p; p += (size_t)KVD * HID * 2;
  u16* Wvb = (u16*)p; p += (size_t)KVD * HID * 2;
  u16* Wob = (u16*)p; p += (size_t)HID * QDIM * 2;
  u16* Qb  = (u16*)p; p += (size_t)SEQN * QDIM * 2;
  u16* Kb  = (u16*)p; p += (size_t)SEQN * KVD * 2;
  u16* Vb  = (u16*)p; p += (size_t)SEQN * KVD * 2;
  u16* Ab  = (u16*)p; p += (size_t)SEQN * QDIM * 2;
  u16* VTg = (u16*)p; p += (size_t)SEQN * KVD * 2;

  cvt_kernel<<<(SEQN*HID/4 + 255)/256, 256, 0, stream>>>(x,  xb,  SEQN*HID/4);
  cvt_kernel<<<(QDIM*HID/4 + 255)/256, 256, 0, stream>>>(Wq, Wqb, QDIM*HID/4);
  cvt_kernel<<<(KVD*HID/4 + 255)/256, 256, 0, stream>>>(Wk, Wkb, KVD*HID/4);
  cvt_kernel<<<(KVD*HID/4 + 255)/256, 256, 0, stream>>>(Wv, Wvb, KVD*HID/4);
  cvt_kernel<<<(HID*QDIM/4 + 255)/256, 256, 0, stream>>>(Wo, Wob, HID*QDIM/4);

  gemm_kernel<0><<<dim3(SEQN/128, QDIM/128), 256, 0, stream>>>(xb, Wqb, Qb, SEQN, QDIM, HID);
  gemm_kernel<0><<<dim3(SEQN/128, KVD/128),  256, 0, stream>>>(xb, Wkb, Kb, SEQN, KVD, HID);
  gemm_kernel<0><<<dim3(SEQN/128, KVD/128),  256, 0, stream>>>(xb, Wvb, Vb, SEQN, KVD, HID);

  rope_kernel<<<(SEQN*NH*64)/256,  256, 0, stream>>>(Qb, NH,  SEQN*NH*64);
  rope_kernel<<<(SEQN*NKV*64)/256, 256, 0, stream>>>(Kb, NKV, SEQN*NKV*64);

  vtrans_kernel<<<dim3(SEQN/64, KVD/64), 256, 0, stream>>>(Vb, VTg);

  attn_kernel<<<dim3(16, NH), 256, 0, stream>>>(Qb, Kb, VTg, Ab);

  gemm_kernel<1><<<dim3(SEQN/128, HID/128), 256, 0, stream>>>(Ab, Wob, d_out, SEQN, HID, QDIM);
}

// Round 8
// 338.463 us; speedup vs baseline: 1.2050x; 1.0931x over previous
//
#include <hip/hip_runtime.h>
#include <hip/hip_bf16.h>

typedef unsigned short u16;
typedef unsigned int u32;
typedef short short8 __attribute__((ext_vector_type(8)));
typedef unsigned short ushort4v __attribute__((ext_vector_type(4)));
typedef float f32x4 __attribute__((ext_vector_type(4)));
typedef float f32x16 __attribute__((ext_vector_type(16)));
typedef u32 u32x4 __attribute__((ext_vector_type(4)));

#define SEQN 4096
#define HID 2048
#define NH 16
#define NKV 4
#define HD 128
#define QDIM 2048   // NH*HD
#define KVD 512     // NKV*HD
#define QKVS 3072   // fused QKV row stride

static __device__ __forceinline__ float bf2f(u16 u){
  unsigned x = ((unsigned)u) << 16; float f; __builtin_memcpy(&f, &x, 4); return f;
}
static __device__ __forceinline__ u16 f2bf(float f){
  unsigned x; __builtin_memcpy(&x, &f, 4);
  x += 0x7fffu + ((x >> 16) & 1u);
  return (u16)(x >> 16);
}
static __device__ __forceinline__ u32 pk2(float a, float b){
  return (u32)f2bf(a) | ((u32)f2bf(b) << 16);
}

// ---------------- fp32 -> bf16 convert ----------------
__global__ __launch_bounds__(256) void cvt_kernel(const float* __restrict__ in, u16* __restrict__ out, int n4){
  int i = blockIdx.x * 256 + threadIdx.x;
  if (i >= n4) return;
  f32x4 v = ((const f32x4*)in)[i];
  ushort4v o;
  o.x = f2bf(v.x); o.y = f2bf(v.y); o.z = f2bf(v.z); o.w = f2bf(v.w);
  ((ushort4v*)out)[i] = o;
}

// ---------------- RoPE (in-place on bf16, strided rows) ----------------
__global__ __launch_bounds__(256) void rope_kernel(u16* __restrict__ X, int stride, int nheads, int total){
  int idx = blockIdx.x * 256 + threadIdx.x;
  if (idx >= total) return;
  int i = idx & 63;          // pair index 0..63
  int rest = idx >> 6;
  int h = rest % nheads;
  int s = rest / nheads;
  float freq = expf(-0.14391156831212788f * (float)i);
  float ang = (float)s * freq;
  float c = cosf(ang), sn = sinf(ang);
  u16* p = X + (size_t)s * stride + (size_t)h * HD + 2 * i;
  float x1 = bf2f(p[0]), x2 = bf2f(p[1]);
  p[0] = f2bf(x1 * c - x2 * sn);
  p[1] = f2bf(x1 * sn + x2 * c);
}

// ---------------- V transpose: V[s][c] (strided) -> VTg[c][s] ----------------
__global__ __launch_bounds__(256) void vtrans_kernel(const u16* __restrict__ V, int vstride, u16* __restrict__ VTg){
  __shared__ u16 T[64][72];
  const int s0 = blockIdx.x * 64;
  const int c0 = blockIdx.y * 64;
  const int tid = threadIdx.x;
  const int sl = tid & 63, ch = tid >> 6;   // ch 0..3
  const u16* src = V + (size_t)(s0 + sl) * vstride + c0 + ch * 16;
  *(short8*)&T[sl][ch * 16]     = *(const short8*)(src);
  *(short8*)&T[sl][ch * 16 + 8] = *(const short8*)(src + 8);
  __syncthreads();
#pragma unroll
  for (int it = 0; it < 16; it++){
    int c = it * 4 + ch;
    VTg[(size_t)(c0 + c) * SEQN + s0 + sl] = T[sl][c];
  }
}

// ---------------- async global->LDS 16B ----------------
static __device__ __forceinline__ void gload16(const void* g, void* l){
  __builtin_amdgcn_global_load_lds((const __attribute__((address_space(1))) void*)g,
                                   (__attribute__((address_space(3))) void*)l, 16, 0, 0);
}

// ---------------- GEMM: C[M][N(ldc)] = A[M][K] * B[N][K]^T ----------------
template<int F32OUT>
__global__ __launch_bounds__(256) void gemm_kernel(const u16* __restrict__ A, const u16* __restrict__ B,
                                                   void* __restrict__ Cout, int M, int N, int Kd, int ldc){
  __shared__ alignas(16) u16 As[128 * 32];
  __shared__ alignas(16) u16 Bs[128 * 32];
  const int tid = threadIdx.x;
  const int w = tid >> 6, l = tid & 63;
  const int wr = w >> 1, wc = w & 1;
  const int lc = l & 15, lg = l >> 4;
  const int tm = blockIdx.x * 128, tn = blockIdx.y * 128;

  const int srow = w * 32 + (l >> 2);
  const int scol = (l & 3) * 8;
  const u16* Ag = A + (size_t)(tm + srow) * Kd + scol;
  const u16* Bg = B + (size_t)(tn + srow) * Kd + scol;
  u16* As0 = As + (w * 2) * 512;
  u16* Bs0 = Bs + (w * 2) * 512;

  f32x4 acc[4][4] = {};

  for (int k0 = 0; k0 < Kd; k0 += 32){
    gload16(Ag + k0,                    As0);
    gload16(Ag + k0 + (size_t)16 * Kd,  As0 + 512);
    gload16(Bg + k0,                    Bs0);
    gload16(Bg + k0 + (size_t)16 * Kd,  Bs0 + 512);
    __syncthreads();
    short8 a[4], b[4];
#pragma unroll
    for (int mi = 0; mi < 4; mi++) a[mi] = *(const short8*)&As[(wr*64 + mi*16 + lc) * 32 + lg*8];
#pragma unroll
    for (int ni = 0; ni < 4; ni++) b[ni] = *(const short8*)&Bs[(wc*64 + ni*16 + lc) * 32 + lg*8];
#pragma unroll
    for (int mi = 0; mi < 4; mi++)
#pragma unroll
      for (int ni = 0; ni < 4; ni++)
        acc[mi][ni] = __builtin_amdgcn_mfma_f32_16x16x32_bf16(a[mi], b[ni], acc[mi][ni], 0, 0, 0);
    __syncthreads();
  }

#pragma unroll
  for (int mi = 0; mi < 4; mi++)
#pragma unroll
    for (int ni = 0; ni < 4; ni++)
#pragma unroll
      for (int r = 0; r < 4; r++){
        int row = tm + wr*64 + mi*16 + lg*4 + r;
        int col = tn + wc*64 + ni*16 + lc;
        float v = acc[mi][ni][r];
        if (F32OUT) ((float*)Cout)[(size_t)row * ldc + col] = v;
        else        ((u16*)Cout)[(size_t)row * ldc + col] = f2bf(v);
      }
}

// ---------------- Flash attention (causal, GQA), 32x32 MFMA, swapped ops ----------------
// 128-thread (2-wave) blocks, grid (32, NH): block x handles q-rows half*64..half*64+63
// (half = x&1) of q-super-block qt = x>>1, then qt = 31-(x>>1) -> every block ~65 staged
// tiles (uniform) -> 512 uniform blocks, 2 independent blocks/CU for stall hiding.
// KV tile 64, double-buffered LDS (1 barrier/tile), single staged reg set 2 tiles ahead.
// K in LDS [64][128], 4-bit chunk-XOR c^(row&15) (2-way = free on read).
// V pre-transposed globally (VTg[c][s]); VT LDS [128][64], chunk-XOR c^(d&7).
// Swapped QK^T -> S^T[kv][q]; per-lane softmax (+1 cross-half shfl); P in registers via
// bf16 pack + shfl_xor(32) half-exchange; swapped PV -> O^T[d][q]. LDS-transpose epilogue.
__global__ __launch_bounds__(128) void attn_kernel(const u16* __restrict__ Qg, const u16* __restrict__ Kgb,
                                                   const u16* __restrict__ VTg, u16* __restrict__ Aout){
  __shared__ alignas(16) char pool[65536];   // 2 x (Ks 16KB + VT 16KB)

  const int pr   = blockIdx.x >> 1;      // 0..15
  const int half = blockIdx.x & 1;
  const int h    = blockIdx.y;
  const int kvh  = h >> 2;
  const int tid  = threadIdx.x;
  const int w = tid >> 6, l = tid & 63;  // w 0..1
  const int q5 = l & 31;
  const int hi = l >> 5;
  const int hi4 = hi * 4;
  const float csc = 0.12751743f;         // (1/sqrt(128)) * log2(e)

  const int krow = tid >> 4;             // 0..7
  const int kch  = tid & 15;
  const int vd   = tid >> 1;             // 0..63
  const int vck  = (tid & 1) * 4;        // V chunk base (0 or 4)

  const u16* Kg = Kgb + kvh * HD + kch * 8;              // row stride QKVS
  const u16* Vg = VTg + (size_t)(kvh * 128) * SEQN;      // [128 d][SEQN]

  short8 kr[8], vr[8];
  auto loadK = [&](int kv0){
#pragma unroll
    for (int it = 0; it < 8; it++)
      kr[it] = *(const short8*)(Kg + (size_t)(kv0 + it * 8 + krow) * QKVS);
  };
  auto loadV = [&](int kv0){
#pragma unroll
    for (int db = 0; db < 2; db++)
#pragma unroll
      for (int c = 0; c < 4; c++)
        vr[db * 4 + c] = *(const short8*)(Vg + (size_t)(db * 64 + vd) * SEQN + kv0 + (vck + c) * 8);
  };
  auto writeT = [&](int b){
    char* Ksb = pool + b * 32768;
    char* VTb = pool + b * 32768 + 16384;
#pragma unroll
    for (int it = 0; it < 8; it++){
      int row = it * 8 + krow;
      *(short8*)(Ksb + row * 256 + ((kch ^ (row & 15)) << 4)) = kr[it];
    }
#pragma unroll
    for (int db = 0; db < 2; db++)
#pragma unroll
      for (int c = 0; c < 4; c++){
        int d = db * 64 + vd;
        int ck = vck + c;
        *(short8*)(VTb + d * 128 + ((ck ^ (d & 7)) << 4)) = vr[db * 4 + c];
      }
  };

  for (int ph = 0; ph < 2; ph++){
    const int qt    = ph ? (31 - pr) : pr;
    const int qbase = qt * 128 + half * 64 + w * 32;
    const int qa    = qbase + q5;
    const int ntiles = 2 * qt + 1 + half;

    // Q fragments (B operand): col = l&31 = q, k = hi*8 + j
    short8 qf[8];
    {
      const u16* qp = Qg + (size_t)(qbase + q5) * QKVS + h * HD + hi * 8;
#pragma unroll
      for (int k0 = 0; k0 < 8; k0++) qf[k0] = *(const short8*)(qp + k0 * 16);
    }

    f32x16 Ov[4] = {};      // O^T: d = nbd*32 + rowmap(r,hi), q = q5
    float Lrow = 0.f;
    float ms = -1e30f;

    auto computeTile = [&](int b, int kv0){
      if (kv0 > qbase + 31) return;
      char* Ksb = pool + b * 32768;
      char* VTb = pool + b * 32768 + 16384;
      // ---- QK^T swapped: S^T[kv][q] ----
      f32x16 Sv[2] = {};
#pragma unroll
      for (int k0 = 0; k0 < 8; k0++){
#pragma unroll
        for (int nb = 0; nb < 2; nb++){
          int kvr = nb * 32 + q5;
          short8 kf = *(const short8*)(Ksb + kvr * 256 + (((k0 * 2 + hi) ^ (kvr & 15)) << 4));
          Sv[nb] = __builtin_amdgcn_mfma_f32_32x32x16_bf16(kf, qf[k0], Sv[nb], 0, 0, 0);
        }
      }
      // ---- causal mask (raw scores) ----
      if (kv0 + 63 > qbase){
#pragma unroll
        for (int nb = 0; nb < 2; nb++)
#pragma unroll
          for (int r = 0; r < 16; r++){
            int kva = kv0 + nb * 32 + (r & 3) + 8 * (r >> 2) + hi4;
            if (kva > qa) Sv[nb][r] = -1e30f;
          }
      }
      // ---- online softmax, scaled-log2 domain, defer-max THR=8 ----
      float tm = -3e38f;
#pragma unroll
      for (int nb = 0; nb < 2; nb++)
#pragma unroll
        for (int r = 0; r < 16; r++) tm = fmaxf(tm, Sv[nb][r]);
      tm = fmaxf(tm, __shfl_xor(tm, 32));
      float tms = tm * csc;
      if (!__all(tms - ms <= 8.f)){
        float nms = fmaxf(ms, tms);
        float al = __builtin_amdgcn_exp2f(ms - nms);
        ms = nms;
        Lrow *= al;
#pragma unroll
        for (int nb = 0; nb < 4; nb++)
#pragma unroll
          for (int r = 0; r < 16; r++) Ov[nb][r] *= al;
      }
      float ts = 0.f;
#pragma unroll
      for (int nb = 0; nb < 2; nb++)
#pragma unroll
        for (int r = 0; r < 16; r++){
          float p = __builtin_amdgcn_exp2f(__builtin_fmaf(Sv[nb][r], csc, -ms));
          Sv[nb][r] = p;
          ts += p;
        }
      ts += __shfl_xor(ts, 32);
      Lrow += ts;
      // ---- P in registers: pack bf16 pairs, exchange halves via shfl_xor(32) ----
#pragma unroll
      for (int kc = 0; kc < 4; kc++){
        const int nb = kc >> 1, rb = (kc & 1) * 8;
        u32 Aw = pk2(Sv[nb][rb + 0], Sv[nb][rb + 1]);
        u32 Bw = pk2(Sv[nb][rb + 2], Sv[nb][rb + 3]);
        u32 Cw = pk2(Sv[nb][rb + 4], Sv[nb][rb + 5]);
        u32 Dw = pk2(Sv[nb][rb + 6], Sv[nb][rb + 7]);
        u32 sAw = __shfl_xor(Aw, 32);
        u32 sBw = __shfl_xor(Bw, 32);
        u32 sCw = __shfl_xor(Cw, 32);
        u32 sDw = __shfl_xor(Dw, 32);
        u32 w0 = hi ? sCw : Aw;
        u32 w1 = hi ? sDw : Bw;
        u32 w2 = hi ? Cw : sAw;
        u32 w3 = hi ? Dw : sBw;
        u32x4 pw4 = {w0, w1, w2, w3};
        short8 pf = *(short8*)&pw4;
        // ---- PV swapped: O^T[d][q] += V^T * P^T ----
#pragma unroll
        for (int nbd = 0; nbd < 4; nbd++){
          int drow = nbd * 32 + q5;
          short8 vf = *(const short8*)(VTb + drow * 128 + (((kc * 2 + hi) ^ (drow & 7)) << 4));
          Ov[nbd] = __builtin_amdgcn_mfma_f32_32x32x16_bf16(vf, pf, Ov[nbd], 0, 0, 0);
        }
      }
    };

    // ---- double-buffered main loop, 1 barrier/tile ----
    loadK(0); loadV(0);
    __syncthreads();                 // prior phase epilogue done (pool reuse)
    writeT(0);
    if (ntiles > 1){ loadK(64); loadV(64); }
    __syncthreads();
    int cur = 0;
    for (int t = 0; t < ntiles; t++){
      if (t + 1 < ntiles) writeT(cur ^ 1);                     // tile t+1 regs -> LDS
      if (t + 2 < ntiles){ loadK((t + 2) * 64); loadV((t + 2) * 64); }
      computeTile(cur, t * 64);
      __syncthreads();
      cur ^= 1;
    }

    // ---- epilogue: normalize, transpose via per-wave LDS reuse, coalesced store ----
    u16* Ew = (u16*)(pool + w * 8704);     // [32 q][136 d] u16
    float rl = 1.f / Lrow;
#pragma unroll
    for (int nbd = 0; nbd < 4; nbd++)
#pragma unroll
      for (int r = 0; r < 16; r += 2){
        int d = nbd * 32 + (r & 3) + 8 * (r >> 2) + hi4;     // even
        u32 wpk = pk2(Ov[nbd][r] * rl, Ov[nbd][r + 1] * rl);
        *(u32*)((char*)Ew + q5 * 272 + d * 2) = wpk;
      }
#pragma unroll
    for (int pass = 0; pass < 8; pass++){
      int q2 = pass * 4 + (l >> 4);
      short8 ov = *(const short8*)((char*)Ew + q2 * 272 + (l & 15) * 16);
      *(short8*)(Aout + (size_t)(qbase + q2) * QDIM + h * HD + (l & 15) * 8) = ov;
    }
    // next phase's prologue barrier protects Ew/pool reuse
  }
}

extern "C" void kernel_launch(void* const* d_in, const int* in_sizes, int n_in,
                              void* d_out, int out_size, void* d_ws, size_t ws_size,
                              hipStream_t stream){
  const float* x  = (const float*)d_in[0];
  const float* Wq = (const float*)d_in[1];
  const float* Wk = (const float*)d_in[2];
  const float* Wv = (const float*)d_in[3];
  const float* Wo = (const float*)d_in[4];

  char* p = (char*)d_ws;
  u16* xb    = (u16*)p; p += (size_t)SEQN * HID * 2;
  u16* Wqkvb = (u16*)p; p += (size_t)QKVS * HID * 2;     // [3072][2048]: Wq|Wk|Wv rows
  u16* Wob   = (u16*)p; p += (size_t)HID * QDIM * 2;
  u16* QKVb  = (u16*)p; p += (size_t)SEQN * QKVS * 2;    // [4096][3072]: Q|K|V cols
  u16* Ab    = (u16*)p; p += (size_t)SEQN * QDIM * 2;
  u16* VTg   = (u16*)p; p += (size_t)SEQN * KVD * 2;

  cvt_kernel<<<(SEQN*HID/4 + 255)/256, 256, 0, stream>>>(x,  xb,  SEQN*HID/4);
  cvt_kernel<<<(QDIM*HID/4 + 255)/256, 256, 0, stream>>>(Wq, Wqkvb,                       QDIM*HID/4);
  cvt_kernel<<<(KVD*HID/4 + 255)/256, 256, 0, stream>>>(Wk, Wqkvb + (size_t)QDIM*HID,     KVD*HID/4);
  cvt_kernel<<<(KVD*HID/4 + 255)/256, 256, 0, stream>>>(Wv, Wqkvb + (size_t)(QDIM+KVD)*HID, KVD*HID/4);
  cvt_kernel<<<(HID*QDIM/4 + 255)/256, 256, 0, stream>>>(Wo, Wob, HID*QDIM/4);

  // fused QKV projection: [4096][3072] = x @ [Wq|Wk|Wv]^T
  gemm_kernel<0><<<dim3(SEQN/128, QKVS/128), 256, 0, stream>>>(xb, Wqkvb, QKVb, SEQN, QKVS, HID, QKVS);

  rope_kernel<<<(SEQN*NH*64)/256,  256, 0, stream>>>(QKVb,        QKVS, NH,  SEQN*NH*64);
  rope_kernel<<<(SEQN*NKV*64)/256, 256, 0, stream>>>(QKVb + QDIM, QKVS, NKV, SEQN*NKV*64);

  vtrans_kernel<<<dim3(SEQN/64, KVD/64), 256, 0, stream>>>(QKVb + QDIM + KVD, QKVS, VTg);

  attn_kernel<<<dim3(32, NH), 128, 0, stream>>>(QKVb, QKVb + QDIM, VTg, Ab);

  gemm_kernel<1><<<dim3(SEQN/128, HID/128), 256, 0, stream>>>(Ab, Wob, d_out, SEQN, HID, QDIM, HID);
}

// Round 9
// 321.527 us; speedup vs baseline: 1.2685x; 1.0527x over previous
//
#include <hip/hip_runtime.h>
#include <hip/hip_bf16.h>

typedef unsigned short u16;
typedef unsigned int u32;
typedef short short8 __attribute__((ext_vector_type(8)));
typedef unsigned short ushort4v __attribute__((ext_vector_type(4)));
typedef float f32x4 __attribute__((ext_vector_type(4)));
typedef float f32x16 __attribute__((ext_vector_type(16)));
typedef u32 u32x4 __attribute__((ext_vector_type(4)));

#define SEQN 4096
#define HID 2048
#define NH 16
#define NKV 4
#define HD 128
#define QDIM 2048   // NH*HD
#define KVD 512     // NKV*HD
#define QKVS 3072   // fused QKV row stride

static __device__ __forceinline__ float bf2f(u16 u){
  unsigned x = ((unsigned)u) << 16; float f; __builtin_memcpy(&f, &x, 4); return f;
}
static __device__ __forceinline__ u16 f2bf(float f){
  unsigned x; __builtin_memcpy(&x, &f, 4);
  x += 0x7fffu + ((x >> 16) & 1u);
  return (u16)(x >> 16);
}
static __device__ __forceinline__ u32 pk2(float a, float b){
  return (u32)f2bf(a) | ((u32)f2bf(b) << 16);
}

// ---------------- fp32 -> bf16 convert ----------------
__global__ __launch_bounds__(256) void cvt_kernel(const float* __restrict__ in, u16* __restrict__ out, int n4){
  int i = blockIdx.x * 256 + threadIdx.x;
  if (i >= n4) return;
  f32x4 v = ((const f32x4*)in)[i];
  ushort4v o;
  o.x = f2bf(v.x); o.y = f2bf(v.y); o.z = f2bf(v.z); o.w = f2bf(v.w);
  ((ushort4v*)out)[i] = o;
}

// ---------------- RoPE (in-place on bf16, strided rows) ----------------
__global__ __launch_bounds__(256) void rope_kernel(u16* __restrict__ X, int stride, int nheads, int total){
  int idx = blockIdx.x * 256 + threadIdx.x;
  if (idx >= total) return;
  int i = idx & 63;
  int rest = idx >> 6;
  int h = rest % nheads;
  int s = rest / nheads;
  float freq = expf(-0.14391156831212788f * (float)i);
  float ang = (float)s * freq;
  float c = cosf(ang), sn = sinf(ang);
  u16* p = X + (size_t)s * stride + (size_t)h * HD + 2 * i;
  float x1 = bf2f(p[0]), x2 = bf2f(p[1]);
  p[0] = f2bf(x1 * c - x2 * sn);
  p[1] = f2bf(x1 * sn + x2 * c);
}

// ---------------- V transpose: V[s][c] (strided) -> VTg[c][s] ----------------
__global__ __launch_bounds__(256) void vtrans_kernel(const u16* __restrict__ V, int vstride, u16* __restrict__ VTg){
  __shared__ u16 T[64][72];
  const int s0 = blockIdx.x * 64;
  const int c0 = blockIdx.y * 64;
  const int tid = threadIdx.x;
  const int sl = tid & 63, ch = tid >> 6;
  const u16* src = V + (size_t)(s0 + sl) * vstride + c0 + ch * 16;
  *(short8*)&T[sl][ch * 16]     = *(const short8*)(src);
  *(short8*)&T[sl][ch * 16 + 8] = *(const short8*)(src + 8);
  __syncthreads();
#pragma unroll
  for (int it = 0; it < 16; it++){
    int c = it * 4 + ch;
    VTg[(size_t)(c0 + c) * SEQN + s0 + sl] = T[sl][c];
  }
}

// ---------------- async global->LDS 16B ----------------
static __device__ __forceinline__ void gload16(const void* g, void* l){
  __builtin_amdgcn_global_load_lds((const __attribute__((address_space(1))) void*)g,
                                   (__attribute__((address_space(3))) void*)l, 16, 0, 0);
}

// ---------------- GEMM: C[M][N(ldc)] = A[M][K] * B[N][K]^T ----------------
template<int F32OUT>
__global__ __launch_bounds__(256) void gemm_kernel(const u16* __restrict__ A, const u16* __restrict__ B,
                                                   void* __restrict__ Cout, int M, int N, int Kd, int ldc){
  __shared__ alignas(16) u16 As[128 * 32];
  __shared__ alignas(16) u16 Bs[128 * 32];
  const int tid = threadIdx.x;
  const int w = tid >> 6, l = tid & 63;
  const int wr = w >> 1, wc = w & 1;
  const int lc = l & 15, lg = l >> 4;
  const int tm = blockIdx.x * 128, tn = blockIdx.y * 128;

  const int srow = w * 32 + (l >> 2);
  const int scol = (l & 3) * 8;
  const u16* Ag = A + (size_t)(tm + srow) * Kd + scol;
  const u16* Bg = B + (size_t)(tn + srow) * Kd + scol;
  u16* As0 = As + (w * 2) * 512;
  u16* Bs0 = Bs + (w * 2) * 512;

  f32x4 acc[4][4] = {};

  for (int k0 = 0; k0 < Kd; k0 += 32){
    gload16(Ag + k0,                    As0);
    gload16(Ag + k0 + (size_t)16 * Kd,  As0 + 512);
    gload16(Bg + k0,                    Bs0);
    gload16(Bg + k0 + (size_t)16 * Kd,  Bs0 + 512);
    __syncthreads();
    short8 a[4], b[4];
#pragma unroll
    for (int mi = 0; mi < 4; mi++) a[mi] = *(const short8*)&As[(wr*64 + mi*16 + lc) * 32 + lg*8];
#pragma unroll
    for (int ni = 0; ni < 4; ni++) b[ni] = *(const short8*)&Bs[(wc*64 + ni*16 + lc) * 32 + lg*8];
#pragma unroll
    for (int mi = 0; mi < 4; mi++)
#pragma unroll
      for (int ni = 0; ni < 4; ni++)
        acc[mi][ni] = __builtin_amdgcn_mfma_f32_16x16x32_bf16(a[mi], b[ni], acc[mi][ni], 0, 0, 0);
    __syncthreads();
  }

#pragma unroll
  for (int mi = 0; mi < 4; mi++)
#pragma unroll
    for (int ni = 0; ni < 4; ni++)
#pragma unroll
      for (int r = 0; r < 4; r++){
        int row = tm + wr*64 + mi*16 + lg*4 + r;
        int col = tn + wc*64 + ni*16 + lc;
        float v = acc[mi][ni][r];
        if (F32OUT) ((float*)Cout)[(size_t)row * ldc + col] = v;
        else        ((u16*)Cout)[(size_t)row * ldc + col] = f2bf(v);
      }
}

// ---------------- Flash attention (causal, GQA), KV-split uniform blocks ----------------
// Grid (16, NH, 2), 256-thread blocks (4 waves x 32 q-rows). Pair (qt_lo=x, qt_hi=31-x)
// has 66 KV tiles total; s=0 runs qt_lo fully (2x+2 tiles, FINAL) + first 31-2x tiles of
// qt_hi (PARTIAL 0); s=1 runs last 33 tiles of qt_hi (PARTIAL 1). Every block stages
// exactly 33 tiles -> 512 uniform blocks, 2 blocks/CU (2 waves/SIMD), staging per CU
// unchanged vs r7. Partials: unnormalized O (bf16) + m,L (f32); combined by combine_kernel.
// KV tile 64 double-buffered (1 barrier/tile), reg-staged 2 ahead. K LDS [64][128] 4-bit
// chunk-XOR; V pre-transposed global, LDS [128][64] 3-bit chunk-XOR. Swapped QK^T/PV,
// per-lane softmax, P in registers via shfl_xor(32) half-exchange.
__global__ __launch_bounds__(256) void attn_kernel(const u16* __restrict__ Qg, const u16* __restrict__ Kgb,
                                                   const u16* __restrict__ VTg, u16* __restrict__ Aout,
                                                   u16* __restrict__ PO, float* __restrict__ mP,
                                                   float* __restrict__ LP){
  __shared__ alignas(16) char pool[65536];   // 2 x (Ks 16KB + VT 16KB)

  const int pr  = blockIdx.x;            // 0..15
  const int h   = blockIdx.y;
  const int s   = blockIdx.z;
  const int kvh = h >> 2;
  const int tid = threadIdx.x;
  const int w = tid >> 6, l = tid & 63;
  const int q5 = l & 31;
  const int hi = l >> 5;
  const int hi4 = hi * 4;
  const float csc = 0.12751743f;         // (1/sqrt(128)) * log2(e)

  const int krow = tid >> 4;             // 0..15
  const int kch  = tid & 15;
  const int vd   = tid >> 1;             // 0..127
  const int vck  = (tid & 1) * 4;

  const u16* Kg = Kgb + kvh * HD + kch * 8;              // row stride QKVS
  const u16* Vg = VTg + (size_t)(kvh * 128 + vd) * SEQN;

  short8 kr[4], vr[4];
  auto loadK = [&](int kv0){
#pragma unroll
    for (int it = 0; it < 4; it++)
      kr[it] = *(const short8*)(Kg + (size_t)(kv0 + it * 16 + krow) * QKVS);
  };
  auto loadV = [&](int kv0){
#pragma unroll
    for (int c = 0; c < 4; c++)
      vr[c] = *(const short8*)(Vg + kv0 + (vck + c) * 8);
  };
  auto writeT = [&](int b){
    char* Ksb = pool + b * 32768;
    char* VTb = pool + b * 32768 + 16384;
#pragma unroll
    for (int it = 0; it < 4; it++){
      int row = it * 16 + krow;
      *(short8*)(Ksb + row * 256 + ((kch ^ (row & 15)) << 4)) = kr[it];
    }
#pragma unroll
    for (int c = 0; c < 4; c++){
      int ck = vck + c;
      *(short8*)(VTb + vd * 128 + ((ck ^ (vd & 7)) << 4)) = vr[c];
    }
  };

  // segment descriptors
  const int qlo = pr, qhi = 31 - pr;
  int nseg, sq[2], st0[2], st1[2], smode[2];   // mode: 0 final, 1 partial0, 2 partial1
  if (s == 0){
    nseg = 2;
    sq[0] = qlo; st0[0] = 0;          st1[0] = 2 * pr + 2;   smode[0] = 0;
    sq[1] = qhi; st0[1] = 0;          st1[1] = 31 - 2 * pr;  smode[1] = 1;
  } else {
    nseg = 1;
    sq[0] = qhi; st0[0] = 31 - 2 * pr; st1[0] = 64 - 2 * pr; smode[0] = 2;
  }

  for (int sg = 0; sg < nseg; sg++){
    const int qt = sq[sg], t0 = st0[sg], t1 = st1[sg], mode = smode[sg];
    const int qbase = qt * 128 + w * 32;
    const int qa    = qbase + q5;

    // Q fragments (B operand): col = l&31 = q, k = hi*8 + j
    short8 qf[8];
    {
      const u16* qp = Qg + (size_t)(qbase + q5) * QKVS + h * HD + hi * 8;
#pragma unroll
      for (int k0 = 0; k0 < 8; k0++) qf[k0] = *(const short8*)(qp + k0 * 16);
    }

    f32x16 Ov[4] = {};
    float Lrow = 0.f;
    float ms = -1e30f;

    auto computeTile = [&](int b, int kv0){
      if (kv0 > qbase + 31) return;
      char* Ksb = pool + b * 32768;
      char* VTb = pool + b * 32768 + 16384;
      f32x16 Sv[2] = {};
#pragma unroll
      for (int k0 = 0; k0 < 8; k0++){
#pragma unroll
        for (int nb = 0; nb < 2; nb++){
          int kvr = nb * 32 + q5;
          short8 kf = *(const short8*)(Ksb + kvr * 256 + (((k0 * 2 + hi) ^ (kvr & 15)) << 4));
          Sv[nb] = __builtin_amdgcn_mfma_f32_32x32x16_bf16(kf, qf[k0], Sv[nb], 0, 0, 0);
        }
      }
      if (kv0 + 63 > qbase){
#pragma unroll
        for (int nb = 0; nb < 2; nb++)
#pragma unroll
          for (int r = 0; r < 16; r++){
            int kva = kv0 + nb * 32 + (r & 3) + 8 * (r >> 2) + hi4;
            if (kva > qa) Sv[nb][r] = -1e30f;
          }
      }
      float tm = -3e38f;
#pragma unroll
      for (int nb = 0; nb < 2; nb++)
#pragma unroll
        for (int r = 0; r < 16; r++) tm = fmaxf(tm, Sv[nb][r]);
      tm = fmaxf(tm, __shfl_xor(tm, 32));
      float tms = tm * csc;
      if (!__all(tms - ms <= 8.f)){
        float nms = fmaxf(ms, tms);
        float al = __builtin_amdgcn_exp2f(ms - nms);
        ms = nms;
        Lrow *= al;
#pragma unroll
        for (int nb = 0; nb < 4; nb++)
#pragma unroll
          for (int r = 0; r < 16; r++) Ov[nb][r] *= al;
      }
      float ts = 0.f;
#pragma unroll
      for (int nb = 0; nb < 2; nb++)
#pragma unroll
        for (int r = 0; r < 16; r++){
          float p = __builtin_amdgcn_exp2f(__builtin_fmaf(Sv[nb][r], csc, -ms));
          Sv[nb][r] = p;
          ts += p;
        }
      ts += __shfl_xor(ts, 32);
      Lrow += ts;
#pragma unroll
      for (int kc = 0; kc < 4; kc++){
        const int nb = kc >> 1, rb = (kc & 1) * 8;
        u32 Aw = pk2(Sv[nb][rb + 0], Sv[nb][rb + 1]);
        u32 Bw = pk2(Sv[nb][rb + 2], Sv[nb][rb + 3]);
        u32 Cw = pk2(Sv[nb][rb + 4], Sv[nb][rb + 5]);
        u32 Dw = pk2(Sv[nb][rb + 6], Sv[nb][rb + 7]);
        u32 sAw = __shfl_xor(Aw, 32);
        u32 sBw = __shfl_xor(Bw, 32);
        u32 sCw = __shfl_xor(Cw, 32);
        u32 sDw = __shfl_xor(Dw, 32);
        u32 w0 = hi ? sCw : Aw;
        u32 w1 = hi ? sDw : Bw;
        u32 w2 = hi ? Cw : sAw;
        u32 w3 = hi ? Dw : sBw;
        u32x4 pw4 = {w0, w1, w2, w3};
        short8 pf = *(short8*)&pw4;
#pragma unroll
        for (int nbd = 0; nbd < 4; nbd++){
          int drow = nbd * 32 + q5;
          short8 vf = *(const short8*)(VTb + drow * 128 + (((kc * 2 + hi) ^ (drow & 7)) << 4));
          Ov[nbd] = __builtin_amdgcn_mfma_f32_32x32x16_bf16(vf, pf, Ov[nbd], 0, 0, 0);
        }
      }
    };

    // ---- double-buffered loop over [t0, t1), 1 barrier/tile ----
    loadK(t0 * 64); loadV(t0 * 64);
    __syncthreads();                 // prior segment's pool reads done
    writeT(0);
    if (t0 + 1 < t1){ loadK((t0 + 1) * 64); loadV((t0 + 1) * 64); }
    __syncthreads();
    int cur = 0;
    for (int t = t0; t < t1; t++){
      if (t + 1 < t1) writeT(cur ^ 1);
      if (t + 2 < t1){ loadK((t + 2) * 64); loadV((t + 2) * 64); }
      computeTile(cur, t * 64);
      __syncthreads();
      cur ^= 1;
    }

    // ---- epilogue: (maybe) normalize, transpose via per-wave LDS, store ----
    u16* Ew = (u16*)(pool + w * 8704);     // [32 q][136 d]
    float rl = (mode == 0) ? (1.f / Lrow) : 1.f;
#pragma unroll
    for (int nbd = 0; nbd < 4; nbd++)
#pragma unroll
      for (int r = 0; r < 16; r += 2){
        int d = nbd * 32 + (r & 3) + 8 * (r >> 2) + hi4;
        u32 wpk = pk2(Ov[nbd][r] * rl, Ov[nbd][r + 1] * rl);
        *(u32*)((char*)Ew + q5 * 272 + d * 2) = wpk;
      }
    if (mode == 0){
#pragma unroll
      for (int pass = 0; pass < 8; pass++){
        int q2 = pass * 4 + (l >> 4);
        short8 ov = *(const short8*)((char*)Ew + q2 * 272 + (l & 15) * 16);
        *(short8*)(Aout + (size_t)(qbase + q2) * QDIM + h * HD + (l & 15) * 8) = ov;
      }
    } else {
      const int p = mode - 1;
      u16* dstb = PO + ((size_t)((p * 16 + pr) * NH + h) * 128) * 128;
#pragma unroll
      for (int pass = 0; pass < 8; pass++){
        int q2 = pass * 4 + (l >> 4);
        short8 ov = *(const short8*)((char*)Ew + q2 * 272 + (l & 15) * 16);
        *(short8*)(dstb + (size_t)(w * 32 + q2) * 128 + (l & 15) * 8) = ov;
      }
      if (hi == 0){
        int idx = ((p * 16 + pr) * NH + h) * 128 + w * 32 + q5;
        mP[idx] = ms;
        LP[idx] = Lrow;
      }
    }
    // next segment's prologue barrier protects pool reuse
  }
}

// ---------------- combine partials for qt_hi = 31 - pr ----------------
__global__ __launch_bounds__(256) void combine_kernel(const u16* __restrict__ PO, const float* __restrict__ mP,
                                                      const float* __restrict__ LP, u16* __restrict__ Aout){
  const int pr = blockIdx.x;
  const int h  = blockIdx.y;
  const int tid = threadIdx.x;
  const int r  = tid >> 1;             // 0..127
  const int dh = (tid & 1) * 64;
  const int qhi = 31 - pr;
  const int idx0 = ((0 * 16 + pr) * NH + h) * 128 + r;
  const int idx1 = ((1 * 16 + pr) * NH + h) * 128 + r;
  float m0 = mP[idx0], m1 = mP[idx1];
  float L0 = LP[idx0], L1 = LP[idx1];
  float M = fmaxf(m0, m1);
  float a0 = __builtin_amdgcn_exp2f(m0 - M);
  float a1 = __builtin_amdgcn_exp2f(m1 - M);
  float rl = 1.f / (L0 * a0 + L1 * a1);
  const u16* o0 = PO + (size_t)idx0 * 128 + dh;
  const u16* o1 = PO + (size_t)idx1 * 128 + dh;
  u16* dst = Aout + (size_t)(qhi * 128 + r) * QDIM + h * HD + dh;
#pragma unroll
  for (int ch = 0; ch < 8; ch++){
    short8 v0 = *(const short8*)(o0 + ch * 8);
    short8 v1 = *(const short8*)(o1 + ch * 8);
    short8 ov;
#pragma unroll
    for (int j = 0; j < 8; j++)
      ov[j] = (short)f2bf((bf2f((u16)v0[j]) * a0 + bf2f((u16)v1[j]) * a1) * rl);
    *(short8*)(dst + ch * 8) = ov;
  }
}

extern "C" void kernel_launch(void* const* d_in, const int* in_sizes, int n_in,
                              void* d_out, int out_size, void* d_ws, size_t ws_size,
                              hipStream_t stream){
  const float* x  = (const float*)d_in[0];
  const float* Wq = (const float*)d_in[1];
  const float* Wk = (const float*)d_in[2];
  const float* Wv = (const float*)d_in[3];
  const float* Wo = (const float*)d_in[4];

  char* p = (char*)d_ws;
  u16* xb    = (u16*)p; p += (size_t)SEQN * HID * 2;
  u16* Wqkvb = (u16*)p; p += (size_t)QKVS * HID * 2;
  u16* Wob   = (u16*)p; p += (size_t)HID * QDIM * 2;
  u16* QKVb  = (u16*)p; p += (size_t)SEQN * QKVS * 2;
  u16* Ab    = (u16*)p; p += (size_t)SEQN * QDIM * 2;
  u16* VTg   = (u16*)p; p += (size_t)SEQN * KVD * 2;
  u16* PO    = (u16*)p; p += (size_t)2 * 16 * NH * 128 * 128 * 2;   // 16 MB
  float* mP  = (float*)p; p += (size_t)2 * 16 * NH * 128 * 4;
  float* LP  = (float*)p; p += (size_t)2 * 16 * NH * 128 * 4;

  cvt_kernel<<<(SEQN*HID/4 + 255)/256, 256, 0, stream>>>(x,  xb,  SEQN*HID/4);
  cvt_kernel<<<(QDIM*HID/4 + 255)/256, 256, 0, stream>>>(Wq, Wqkvb,                         QDIM*HID/4);
  cvt_kernel<<<(KVD*HID/4 + 255)/256, 256, 0, stream>>>(Wk, Wqkvb + (size_t)QDIM*HID,       KVD*HID/4);
  cvt_kernel<<<(KVD*HID/4 + 255)/256, 256, 0, stream>>>(Wv, Wqkvb + (size_t)(QDIM+KVD)*HID, KVD*HID/4);
  cvt_kernel<<<(HID*QDIM/4 + 255)/256, 256, 0, stream>>>(Wo, Wob, HID*QDIM/4);

  gemm_kernel<0><<<dim3(SEQN/128, QKVS/128), 256, 0, stream>>>(xb, Wqkvb, QKVb, SEQN, QKVS, HID, QKVS);

  rope_kernel<<<(SEQN*NH*64)/256,  256, 0, stream>>>(QKVb,        QKVS, NH,  SEQN*NH*64);
  rope_kernel<<<(SEQN*NKV*64)/256, 256, 0, stream>>>(QKVb + QDIM, QKVS, NKV, SEQN*NKV*64);

  vtrans_kernel<<<dim3(SEQN/64, KVD/64), 256, 0, stream>>>(QKVb + QDIM + KVD, QKVS, VTg);

  attn_kernel<<<dim3(16, NH, 2), 256, 0, stream>>>(QKVb, QKVb + QDIM, VTg, Ab, PO, mP, LP);
  combine_kernel<<<dim3(16, NH), 256, 0, stream>>>(PO, mP, LP, Ab);

  gemm_kernel<1><<<dim3(SEQN/128, HID/128), 256, 0, stream>>>(Ab, Wob, d_out, SEQN, HID, QDIM, HID);
}

// Round 10
// 266.984 us; speedup vs baseline: 1.5276x; 1.2043x over previous
//
#include <hip/hip_runtime.h>
#include <hip/hip_bf16.h>

typedef unsigned short u16;
typedef unsigned int u32;
typedef short short8 __attribute__((ext_vector_type(8)));
typedef unsigned short ushort4v __attribute__((ext_vector_type(4)));
typedef float f32x4 __attribute__((ext_vector_type(4)));
typedef float f32x16 __attribute__((ext_vector_type(16)));
typedef u32 u32x4 __attribute__((ext_vector_type(4)));

#define SEQN 4096
#define HID 2048
#define NH 16
#define NKV 4
#define HD 128
#define QDIM 2048   // NH*HD
#define KVD 512     // NKV*HD
#define QKVS 3072   // fused QKV row stride

static __device__ __forceinline__ float bf2f(u16 u){
  unsigned x = ((unsigned)u) << 16; float f; __builtin_memcpy(&f, &x, 4); return f;
}
static __device__ __forceinline__ u16 f2bf(float f){
  unsigned x; __builtin_memcpy(&x, &f, 4);
  x += 0x7fffu + ((x >> 16) & 1u);
  return (u16)(x >> 16);
}
static __device__ __forceinline__ u32 pk2(float a, float b){
  return (u32)f2bf(a) | ((u32)f2bf(b) << 16);
}

// ---------------- fp32 -> bf16 convert ----------------
__global__ __launch_bounds__(256) void cvt_kernel(const float* __restrict__ in, u16* __restrict__ out, int n4){
  int i = blockIdx.x * 256 + threadIdx.x;
  if (i >= n4) return;
  f32x4 v = ((const f32x4*)in)[i];
  ushort4v o;
  o.x = f2bf(v.x); o.y = f2bf(v.y); o.z = f2bf(v.z); o.w = f2bf(v.w);
  ((ushort4v*)out)[i] = o;
}

// ---------------- RoPE (in-place on bf16, strided rows) ----------------
__global__ __launch_bounds__(256) void rope_kernel(u16* __restrict__ X, int stride, int nheads, int total){
  int idx = blockIdx.x * 256 + threadIdx.x;
  if (idx >= total) return;
  int i = idx & 63;
  int rest = idx >> 6;
  int h = rest % nheads;
  int s = rest / nheads;
  float freq = expf(-0.14391156831212788f * (float)i);
  float ang = (float)s * freq;
  float c = cosf(ang), sn = sinf(ang);
  u16* p = X + (size_t)s * stride + (size_t)h * HD + 2 * i;
  float x1 = bf2f(p[0]), x2 = bf2f(p[1]);
  p[0] = f2bf(x1 * c - x2 * sn);
  p[1] = f2bf(x1 * sn + x2 * c);
}

// ---------------- V transpose: V[s][c] (strided) -> VTg[c][s] ----------------
__global__ __launch_bounds__(256) void vtrans_kernel(const u16* __restrict__ V, int vstride, u16* __restrict__ VTg){
  __shared__ u16 T[64][72];
  const int s0 = blockIdx.x * 64;
  const int c0 = blockIdx.y * 64;
  const int tid = threadIdx.x;
  const int sl = tid & 63, ch = tid >> 6;
  const u16* src = V + (size_t)(s0 + sl) * vstride + c0 + ch * 16;
  *(short8*)&T[sl][ch * 16]     = *(const short8*)(src);
  *(short8*)&T[sl][ch * 16 + 8] = *(const short8*)(src + 8);
  __syncthreads();
#pragma unroll
  for (int it = 0; it < 16; it++){
    int c = it * 4 + ch;
    VTg[(size_t)(c0 + c) * SEQN + s0 + sl] = T[sl][c];
  }
}

// ---------------- async global->LDS 16B ----------------
static __device__ __forceinline__ void gload16(const void* g, void* l){
  __builtin_amdgcn_global_load_lds((const __attribute__((address_space(1))) void*)g,
                                   (__attribute__((address_space(3))) void*)l, 16, 0, 0);
}

// ---------------- GEMM: C[M][N(ldc)] = A[M][K] * B[N][K]^T ----------------
template<int F32OUT>
__global__ __launch_bounds__(256) void gemm_kernel(const u16* __restrict__ A, const u16* __restrict__ B,
                                                   void* __restrict__ Cout, int M, int N, int Kd, int ldc){
  __shared__ alignas(16) u16 As[128 * 32];
  __shared__ alignas(16) u16 Bs[128 * 32];
  const int tid = threadIdx.x;
  const int w = tid >> 6, l = tid & 63;
  const int wr = w >> 1, wc = w & 1;
  const int lc = l & 15, lg = l >> 4;
  const int tm = blockIdx.x * 128, tn = blockIdx.y * 128;

  const int srow = w * 32 + (l >> 2);
  const int scol = (l & 3) * 8;
  const u16* Ag = A + (size_t)(tm + srow) * Kd + scol;
  const u16* Bg = B + (size_t)(tn + srow) * Kd + scol;
  u16* As0 = As + (w * 2) * 512;
  u16* Bs0 = Bs + (w * 2) * 512;

  f32x4 acc[4][4] = {};

  for (int k0 = 0; k0 < Kd; k0 += 32){
    gload16(Ag + k0,                    As0);
    gload16(Ag + k0 + (size_t)16 * Kd,  As0 + 512);
    gload16(Bg + k0,                    Bs0);
    gload16(Bg + k0 + (size_t)16 * Kd,  Bs0 + 512);
    __syncthreads();
    short8 a[4], b[4];
#pragma unroll
    for (int mi = 0; mi < 4; mi++) a[mi] = *(const short8*)&As[(wr*64 + mi*16 + lc) * 32 + lg*8];
#pragma unroll
    for (int ni = 0; ni < 4; ni++) b[ni] = *(const short8*)&Bs[(wc*64 + ni*16 + lc) * 32 + lg*8];
#pragma unroll
    for (int mi = 0; mi < 4; mi++)
#pragma unroll
      for (int ni = 0; ni < 4; ni++)
        acc[mi][ni] = __builtin_amdgcn_mfma_f32_16x16x32_bf16(a[mi], b[ni], acc[mi][ni], 0, 0, 0);
    __syncthreads();
  }

#pragma unroll
  for (int mi = 0; mi < 4; mi++)
#pragma unroll
    for (int ni = 0; ni < 4; ni++)
#pragma unroll
      for (int r = 0; r < 4; r++){
        int row = tm + wr*64 + mi*16 + lg*4 + r;
        int col = tn + wc*64 + ni*16 + lc;
        float v = acc[mi][ni][r];
        if (F32OUT) ((float*)Cout)[(size_t)row * ldc + col] = v;
        else        ((u16*)Cout)[(size_t)row * ldc + col] = f2bf(v);
      }
}

// ---------------- Flash attention (causal, GQA), KV-split uniform blocks ----------------
// Grid (16, NH, 2), 256-thread blocks, __launch_bounds__(256,2) caps regs at 256/wave so
// TWO blocks co-reside per CU (2 waves/SIMD). Staging is pure global_load_lds with
// pre-swizzled per-lane SOURCE + linear LDS dest (T2/m173): no staging registers, no
// ds_writes. KV tile 64 double-buffered, 1 barrier/tile. K LDS [64][128] 4-bit chunk-XOR;
// V pre-transposed global, LDS [128][64] 3-bit chunk-XOR. Swapped QK^T/PV, per-lane
// softmax, P in registers via shfl_xor(32) half-exchange. Partials (qt_hi) combined
// by combine_kernel.
__global__ __launch_bounds__(256, 2) void attn_kernel(const u16* __restrict__ Qg, const u16* __restrict__ Kgb,
                                                      const u16* __restrict__ VTg, u16* __restrict__ Aout,
                                                      u16* __restrict__ PO, float* __restrict__ mP,
                                                      float* __restrict__ LP){
  __shared__ alignas(16) char pool[65536];   // 2 x (Ks 16KB + VT 16KB)

  const int pr  = blockIdx.x;            // 0..15
  const int h   = blockIdx.y;
  const int s   = blockIdx.z;
  const int kvh = h >> 2;
  const int tid = threadIdx.x;
  const int w = tid >> 6, l = tid & 63;
  const int q5 = l & 31;
  const int hi = l >> 5;
  const int hi4 = hi * 4;
  const float csc = 0.12751743f;         // (1/sqrt(128)) * log2(e)

  // ---- pre-swizzled per-lane global sources for global_load_lds (linear LDS dest) ----
  // K: LDS chunk-block blk = w*4+i covers rows blk*4..blk*4+3; lane l -> row blk*4+(l>>4),
  //    chunk c=l&15 holds global chunk c^(row&15).
  // V: blk covers d-rows blk*8..blk*8+7; lane l -> d = blk*8+(l>>3), chunk c=l&7 holds
  //    global chunk c^(d&7).
  const u16* Ksrc[4];
  const u16* Vsrc[4];
#pragma unroll
  for (int i = 0; i < 4; i++){
    int blk = w * 4 + i;
    int row = blk * 4 + (l >> 4);
    int cg  = (l & 15) ^ (row & 15);
    Ksrc[i] = Kgb + (size_t)row * QKVS + kvh * HD + cg * 8;
    int d   = blk * 8 + (l >> 3);
    int cv  = (l & 7) ^ (d & 7);
    Vsrc[i] = VTg + (size_t)(kvh * 128 + d) * SEQN + cv * 8;
  }

  auto issueTile = [&](int b, int kv0){
    char* Ksb = pool + b * 32768;
    char* VTb = Ksb + 16384;
#pragma unroll
    for (int i = 0; i < 4; i++)
      gload16(Ksrc[i] + (size_t)kv0 * QKVS, Ksb + (w * 4 + i) * 1024);
#pragma unroll
    for (int i = 0; i < 4; i++)
      gload16(Vsrc[i] + kv0, VTb + (w * 4 + i) * 1024);
  };

  // segment descriptors
  const int qlo = pr, qhi = 31 - pr;
  int nseg, sq[2], st0[2], st1[2], smode[2];   // mode: 0 final, 1 partial0, 2 partial1
  if (s == 0){
    nseg = 2;
    sq[0] = qlo; st0[0] = 0;           st1[0] = 2 * pr + 2;   smode[0] = 0;
    sq[1] = qhi; st0[1] = 0;           st1[1] = 31 - 2 * pr;  smode[1] = 1;
  } else {
    nseg = 1;
    sq[0] = qhi; st0[0] = 31 - 2 * pr; st1[0] = 64 - 2 * pr;  smode[0] = 2;
  }

  for (int sg = 0; sg < nseg; sg++){
    const int qt = sq[sg], t0 = st0[sg], t1 = st1[sg], mode = smode[sg];
    const int qbase = qt * 128 + w * 32;
    const int qa    = qbase + q5;

    // Q fragments (B operand): col = l&31 = q, k = hi*8 + j
    short8 qf[8];
    {
      const u16* qp = Qg + (size_t)(qbase + q5) * QKVS + h * HD + hi * 8;
#pragma unroll
      for (int k0 = 0; k0 < 8; k0++) qf[k0] = *(const short8*)(qp + k0 * 16);
    }

    f32x16 Ov[4] = {};
    float Lrow = 0.f;
    float ms = -1e30f;

    auto computeTile = [&](int b, int kv0){
      if (kv0 > qbase + 31) return;
      char* Ksb = pool + b * 32768;
      char* VTb = Ksb + 16384;
      f32x16 Sv[2] = {};
#pragma unroll
      for (int k0 = 0; k0 < 8; k0++){
#pragma unroll
        for (int nb = 0; nb < 2; nb++){
          int kvr = nb * 32 + q5;
          short8 kf = *(const short8*)(Ksb + kvr * 256 + (((k0 * 2 + hi) ^ (kvr & 15)) << 4));
          Sv[nb] = __builtin_amdgcn_mfma_f32_32x32x16_bf16(kf, qf[k0], Sv[nb], 0, 0, 0);
        }
      }
      if (kv0 + 63 > qbase){
#pragma unroll
        for (int nb = 0; nb < 2; nb++)
#pragma unroll
          for (int r = 0; r < 16; r++){
            int kva = kv0 + nb * 32 + (r & 3) + 8 * (r >> 2) + hi4;
            if (kva > qa) Sv[nb][r] = -1e30f;
          }
      }
      float tm = -3e38f;
#pragma unroll
      for (int nb = 0; nb < 2; nb++)
#pragma unroll
        for (int r = 0; r < 16; r++) tm = fmaxf(tm, Sv[nb][r]);
      tm = fmaxf(tm, __shfl_xor(tm, 32));
      float tms = tm * csc;
      if (!__all(tms - ms <= 8.f)){
        float nms = fmaxf(ms, tms);
        float al = __builtin_amdgcn_exp2f(ms - nms);
        ms = nms;
        Lrow *= al;
#pragma unroll
        for (int nb = 0; nb < 4; nb++)
#pragma unroll
          for (int r = 0; r < 16; r++) Ov[nb][r] *= al;
      }
      float ts = 0.f;
#pragma unroll
      for (int nb = 0; nb < 2; nb++)
#pragma unroll
        for (int r = 0; r < 16; r++){
          float p = __builtin_amdgcn_exp2f(__builtin_fmaf(Sv[nb][r], csc, -ms));
          Sv[nb][r] = p;
          ts += p;
        }
      ts += __shfl_xor(ts, 32);
      Lrow += ts;
#pragma unroll
      for (int kc = 0; kc < 4; kc++){
        const int nb = kc >> 1, rb = (kc & 1) * 8;
        u32 Aw = pk2(Sv[nb][rb + 0], Sv[nb][rb + 1]);
        u32 Bw = pk2(Sv[nb][rb + 2], Sv[nb][rb + 3]);
        u32 Cw = pk2(Sv[nb][rb + 4], Sv[nb][rb + 5]);
        u32 Dw = pk2(Sv[nb][rb + 6], Sv[nb][rb + 7]);
        u32 sAw = __shfl_xor(Aw, 32);
        u32 sBw = __shfl_xor(Bw, 32);
        u32 sCw = __shfl_xor(Cw, 32);
        u32 sDw = __shfl_xor(Dw, 32);
        u32 w0 = hi ? sCw : Aw;
        u32 w1 = hi ? sDw : Bw;
        u32 w2 = hi ? Cw : sAw;
        u32 w3 = hi ? Dw : sBw;
        u32x4 pw4 = {w0, w1, w2, w3};
        short8 pf = *(short8*)&pw4;
#pragma unroll
        for (int nbd = 0; nbd < 4; nbd++){
          int drow = nbd * 32 + q5;
          short8 vf = *(const short8*)(VTb + drow * 128 + (((kc * 2 + hi) ^ (drow & 7)) << 4));
          Ov[nbd] = __builtin_amdgcn_mfma_f32_32x32x16_bf16(vf, pf, Ov[nbd], 0, 0, 0);
        }
      }
    };

    // ---- double-buffered loop over [t0, t1), 1 barrier/tile, async staging ----
    __syncthreads();                 // prior segment's pool reads done
    issueTile(0, t0 * 64);
    __syncthreads();                 // buf0 landed (barrier drains vmcnt)
    int cur = 0;
    for (int t = t0; t < t1; t++){
      if (t + 1 < t1) issueTile(cur ^ 1, (t + 1) * 64);
      computeTile(cur, t * 64);
      __syncthreads();               // drains next tile's loads; buf swap safe
      cur ^= 1;
    }

    // ---- epilogue: (maybe) normalize, transpose via per-wave LDS, store ----
    u16* Ew = (u16*)(pool + w * 8704);     // [32 q][136 d]
    float rl = (mode == 0) ? (1.f / Lrow) : 1.f;
#pragma unroll
    for (int nbd = 0; nbd < 4; nbd++)
#pragma unroll
      for (int r = 0; r < 16; r += 2){
        int d = nbd * 32 + (r & 3) + 8 * (r >> 2) + hi4;
        u32 wpk = pk2(Ov[nbd][r] * rl, Ov[nbd][r + 1] * rl);
        *(u32*)((char*)Ew + q5 * 272 + d * 2) = wpk;
      }
    if (mode == 0){
#pragma unroll
      for (int pass = 0; pass < 8; pass++){
        int q2 = pass * 4 + (l >> 4);
        short8 ov = *(const short8*)((char*)Ew + q2 * 272 + (l & 15) * 16);
        *(short8*)(Aout + (size_t)(qbase + q2) * QDIM + h * HD + (l & 15) * 8) = ov;
      }
    } else {
      const int p = mode - 1;
      u16* dstb = PO + ((size_t)((p * 16 + pr) * NH + h) * 128) * 128;
#pragma unroll
      for (int pass = 0; pass < 8; pass++){
        int q2 = pass * 4 + (l >> 4);
        short8 ov = *(const short8*)((char*)Ew + q2 * 272 + (l & 15) * 16);
        *(short8*)(dstb + (size_t)(w * 32 + q2) * 128 + (l & 15) * 8) = ov;
      }
      if (hi == 0){
        int idx = ((p * 16 + pr) * NH + h) * 128 + w * 32 + q5;
        mP[idx] = ms;
        LP[idx] = Lrow;
      }
    }
  }
}

// ---------------- combine partials for qt_hi = 31 - pr ----------------
__global__ __launch_bounds__(256) void combine_kernel(const u16* __restrict__ PO, const float* __restrict__ mP,
                                                      const float* __restrict__ LP, u16* __restrict__ Aout){
  const int pr = blockIdx.x;
  const int h  = blockIdx.y;
  const int tid = threadIdx.x;
  const int r  = tid >> 1;             // 0..127
  const int dh = (tid & 1) * 64;
  const int qhi = 31 - pr;
  const int idx0 = ((0 * 16 + pr) * NH + h) * 128 + r;
  const int idx1 = ((1 * 16 + pr) * NH + h) * 128 + r;
  float m0 = mP[idx0], m1 = mP[idx1];
  float L0 = LP[idx0], L1 = LP[idx1];
  float M = fmaxf(m0, m1);
  float a0 = __builtin_amdgcn_exp2f(m0 - M);
  float a1 = __builtin_amdgcn_exp2f(m1 - M);
  float rl = 1.f / (L0 * a0 + L1 * a1);
  const u16* o0 = PO + (size_t)idx0 * 128 + dh;
  const u16* o1 = PO + (size_t)idx1 * 128 + dh;
  u16* dst = Aout + (size_t)(qhi * 128 + r) * QDIM + h * HD + dh;
#pragma unroll
  for (int ch = 0; ch < 8; ch++){
    short8 v0 = *(const short8*)(o0 + ch * 8);
    short8 v1 = *(const short8*)(o1 + ch * 8);
    short8 ov;
#pragma unroll
    for (int j = 0; j < 8; j++)
      ov[j] = (short)f2bf((bf2f((u16)v0[j]) * a0 + bf2f((u16)v1[j]) * a1) * rl);
    *(short8*)(dst + ch * 8) = ov;
  }
}

extern "C" void kernel_launch(void* const* d_in, const int* in_sizes, int n_in,
                              void* d_out, int out_size, void* d_ws, size_t ws_size,
                              hipStream_t stream){
  const float* x  = (const float*)d_in[0];
  const float* Wq = (const float*)d_in[1];
  const float* Wk = (const float*)d_in[2];
  const float* Wv = (const float*)d_in[3];
  const float* Wo = (const float*)d_in[4];

  char* p = (char*)d_ws;
  u16* xb    = (u16*)p; p += (size_t)SEQN * HID * 2;
  u16* Wqkvb = (u16*)p; p += (size_t)QKVS * HID * 2;
  u16* Wob   = (u16*)p; p += (size_t)HID * QDIM * 2;
  u16* QKVb  = (u16*)p; p += (size_t)SEQN * QKVS * 2;
  u16* Ab    = (u16*)p; p += (size_t)SEQN * QDIM * 2;
  u16* VTg   = (u16*)p; p += (size_t)SEQN * KVD * 2;
  u16* PO    = (u16*)p; p += (size_t)2 * 16 * NH * 128 * 128 * 2;   // 16 MB
  float* mP  = (float*)p; p += (size_t)2 * 16 * NH * 128 * 4;
  float* LP  = (float*)p; p += (size_t)2 * 16 * NH * 128 * 4;

  cvt_kernel<<<(SEQN*HID/4 + 255)/256, 256, 0, stream>>>(x,  xb,  SEQN*HID/4);
  cvt_kernel<<<(QDIM*HID/4 + 255)/256, 256, 0, stream>>>(Wq, Wqkvb,                         QDIM*HID/4);
  cvt_kernel<<<(KVD*HID/4 + 255)/256, 256, 0, stream>>>(Wk, Wqkvb + (size_t)QDIM*HID,       KVD*HID/4);
  cvt_kernel<<<(KVD*HID/4 + 255)/256, 256, 0, stream>>>(Wv, Wqkvb + (size_t)(QDIM+KVD)*HID, KVD*HID/4);
  cvt_kernel<<<(HID*QDIM/4 + 255)/256, 256, 0, stream>>>(Wo, Wob, HID*QDIM/4);

  gemm_kernel<0><<<dim3(SEQN/128, QKVS/128), 256, 0, stream>>>(xb, Wqkvb, QKVb, SEQN, QKVS, HID, QKVS);

  rope_kernel<<<(SEQN*NH*64)/256,  256, 0, stream>>>(QKVb,        QKVS, NH,  SEQN*NH*64);
  rope_kernel<<<(SEQN*NKV*64)/256, 256, 0, stream>>>(QKVb + QDIM, QKVS, NKV, SEQN*NKV*64);

  vtrans_kernel<<<dim3(SEQN/64, KVD/64), 256, 0, stream>>>(QKVb + QDIM + KVD, QKVS, VTg);

  attn_kernel<<<dim3(16, NH, 2), 256, 0, stream>>>(QKVb, QKVb + QDIM, VTg, Ab, PO, mP, LP);
  combine_kernel<<<dim3(16, NH), 256, 0, stream>>>(PO, mP, LP, Ab);

  gemm_kernel<1><<<dim3(SEQN/128, HID/128), 256, 0, stream>>>(Ab, Wob, d_out, SEQN, HID, QDIM, HID);
}

// Round 11
// 266.118 us; speedup vs baseline: 1.5326x; 1.0033x over previous
//
#include <hip/hip_runtime.h>
#include <hip/hip_bf16.h>

typedef unsigned short u16;
typedef unsigned int u32;
typedef short short8 __attribute__((ext_vector_type(8)));
typedef unsigned short ushort4v __attribute__((ext_vector_type(4)));
typedef float f32x4 __attribute__((ext_vector_type(4)));
typedef float f32x16 __attribute__((ext_vector_type(16)));
typedef u32 u32x4 __attribute__((ext_vector_type(4)));

#define SEQN 4096
#define HID 2048
#define NH 16
#define NKV 4
#define HD 128
#define QDIM 2048   // NH*HD
#define KVD 512     // NKV*HD
#define QKVS 3072   // fused QKV row stride

static __device__ __forceinline__ float bf2f(u16 u){
  unsigned x = ((unsigned)u) << 16; float f; __builtin_memcpy(&f, &x, 4); return f;
}
static __device__ __forceinline__ u16 f2bf(float f){
  unsigned x; __builtin_memcpy(&x, &f, 4);
  x += 0x7fffu + ((x >> 16) & 1u);
  return (u16)(x >> 16);
}
static __device__ __forceinline__ u32 pk2(float a, float b){
  return (u32)f2bf(a) | ((u32)f2bf(b) << 16);
}

// ---------------- fused fp32 -> bf16 convert (all 5 inputs, one launch) ----------------
#define G1 (SEQN*HID/4)
#define G2 (QDIM*HID/4)
#define G3 (KVD*HID/4)
#define G4 (KVD*HID/4)
#define G5 (HID*QDIM/4)
__global__ __launch_bounds__(256) void cvt5_kernel(const float* __restrict__ x,  const float* __restrict__ Wq,
                                                   const float* __restrict__ Wk, const float* __restrict__ Wv,
                                                   const float* __restrict__ Wo, u16* __restrict__ xb,
                                                   u16* __restrict__ Wqkvb, u16* __restrict__ Wob){
  int g = blockIdx.x * 256 + threadIdx.x;
  const float* src; u16* dst; int off;
  if (g < G1)                { src = x;  dst = xb;    off = g; }
  else if (g < G1+G2)        { src = Wq; dst = Wqkvb; off = g - G1; }
  else if (g < G1+G2+G3)     { src = Wk; dst = Wqkvb + (size_t)QDIM*HID/4*4;        off = g - (G1+G2); }
  else if (g < G1+G2+G3+G4)  { src = Wv; dst = Wqkvb + (size_t)(QDIM+KVD)*HID/4*4;  off = g - (G1+G2+G3); }
  else if (g < G1+G2+G3+G4+G5){ src = Wo; dst = Wob;  off = g - (G1+G2+G3+G4); }
  else return;
  f32x4 v = ((const f32x4*)src)[off];
  ushort4v o;
  o.x = f2bf(v.x); o.y = f2bf(v.y); o.z = f2bf(v.z); o.w = f2bf(v.w);
  ((ushort4v*)dst)[off] = o;
}

// ---------------- RoPE (Q and K in one launch, strided QKV rows) ----------------
__global__ __launch_bounds__(256) void rope2_kernel(u16* __restrict__ QKVb){
  int idx = blockIdx.x * 256 + threadIdx.x;
  if (idx >= SEQN * (NH + NKV) * 64) return;
  int i = idx & 63;
  int rest = idx >> 6;
  int h = rest % (NH + NKV);
  int s = rest / (NH + NKV);
  float freq = expf(-0.14391156831212788f * (float)i);
  float ang = (float)s * freq;
  float c = cosf(ang), sn = sinf(ang);
  int col = (h < NH) ? h * HD : QDIM + (h - NH) * HD;
  u16* p = QKVb + (size_t)s * QKVS + col + 2 * i;
  float x1 = bf2f(p[0]), x2 = bf2f(p[1]);
  p[0] = f2bf(x1 * c - x2 * sn);
  p[1] = f2bf(x1 * sn + x2 * c);
}

// ---------------- V transpose: V[s][c] (strided) -> VTg[c][s] ----------------
__global__ __launch_bounds__(256) void vtrans_kernel(const u16* __restrict__ V, int vstride, u16* __restrict__ VTg){
  __shared__ u16 T[64][72];
  const int s0 = blockIdx.x * 64;
  const int c0 = blockIdx.y * 64;
  const int tid = threadIdx.x;
  const int sl = tid & 63, ch = tid >> 6;
  const u16* src = V + (size_t)(s0 + sl) * vstride + c0 + ch * 16;
  *(short8*)&T[sl][ch * 16]     = *(const short8*)(src);
  *(short8*)&T[sl][ch * 16 + 8] = *(const short8*)(src + 8);
  __syncthreads();
#pragma unroll
  for (int it = 0; it < 16; it++){
    int c = it * 4 + ch;
    VTg[(size_t)(c0 + c) * SEQN + s0 + sl] = T[sl][c];
  }
}

// ---------------- async global->LDS 16B ----------------
static __device__ __forceinline__ void gload16(const void* g, void* l){
  __builtin_amdgcn_global_load_lds((const __attribute__((address_space(1))) void*)g,
                                   (__attribute__((address_space(3))) void*)l, 16, 0, 0);
}

// ---------------- GEMM: C[M][N(ldc)] = A[M][K] * B[N][K]^T ----------------
template<int F32OUT>
__global__ __launch_bounds__(256) void gemm_kernel(const u16* __restrict__ A, const u16* __restrict__ B,
                                                   void* __restrict__ Cout, int M, int N, int Kd, int ldc){
  __shared__ alignas(16) u16 As[128 * 32];
  __shared__ alignas(16) u16 Bs[128 * 32];
  const int tid = threadIdx.x;
  const int w = tid >> 6, l = tid & 63;
  const int wr = w >> 1, wc = w & 1;
  const int lc = l & 15, lg = l >> 4;
  const int tm = blockIdx.x * 128, tn = blockIdx.y * 128;

  const int srow = w * 32 + (l >> 2);
  const int scol = (l & 3) * 8;
  const u16* Ag = A + (size_t)(tm + srow) * Kd + scol;
  const u16* Bg = B + (size_t)(tn + srow) * Kd + scol;
  u16* As0 = As + (w * 2) * 512;
  u16* Bs0 = Bs + (w * 2) * 512;

  f32x4 acc[4][4] = {};

  for (int k0 = 0; k0 < Kd; k0 += 32){
    gload16(Ag + k0,                    As0);
    gload16(Ag + k0 + (size_t)16 * Kd,  As0 + 512);
    gload16(Bg + k0,                    Bs0);
    gload16(Bg + k0 + (size_t)16 * Kd,  Bs0 + 512);
    __syncthreads();
    short8 a[4], b[4];
#pragma unroll
    for (int mi = 0; mi < 4; mi++) a[mi] = *(const short8*)&As[(wr*64 + mi*16 + lc) * 32 + lg*8];
#pragma unroll
    for (int ni = 0; ni < 4; ni++) b[ni] = *(const short8*)&Bs[(wc*64 + ni*16 + lc) * 32 + lg*8];
#pragma unroll
    for (int mi = 0; mi < 4; mi++)
#pragma unroll
      for (int ni = 0; ni < 4; ni++)
        acc[mi][ni] = __builtin_amdgcn_mfma_f32_16x16x32_bf16(a[mi], b[ni], acc[mi][ni], 0, 0, 0);
    __syncthreads();
  }

#pragma unroll
  for (int mi = 0; mi < 4; mi++)
#pragma unroll
    for (int ni = 0; ni < 4; ni++)
#pragma unroll
      for (int r = 0; r < 4; r++){
        int row = tm + wr*64 + mi*16 + lg*4 + r;
        int col = tn + wc*64 + ni*16 + lc;
        float v = acc[mi][ni][r];
        if (F32OUT) ((float*)Cout)[(size_t)row * ldc + col] = v;
        else        ((u16*)Cout)[(size_t)row * ldc + col] = f2bf(v);
      }
}

// ---------------- Flash attention (causal, GQA), att[2]-pipelined ----------------
// Grid (16, NH, 2), 256 threads, launch_bounds(256,2) -> 2 blocks/CU. KV-split uniform
// work as r10 (33 staged tiles/block). NEW: one-tile-deferred softmax+PV (T15): per iter
// issue stage(t+1) -> QK^T(t) -> finish(t-1); QK MFMA overlaps finish's VALU chain.
// Buffers: K double (2x16KB), V TRIPLE (3x16KB) = 80KB LDS (exactly 2 blocks/CU).
// Staging via global_load_lds, pre-swizzled source + linear LDS dest. Swapped QK^T/PV,
// per-lane softmax, P in registers via shfl_xor(32) half-exchange.
__global__ __launch_bounds__(256, 2) void attn_kernel(const u16* __restrict__ Qg, const u16* __restrict__ Kgb,
                                                      const u16* __restrict__ VTg, u16* __restrict__ Aout,
                                                      u16* __restrict__ PO, float* __restrict__ mP,
                                                      float* __restrict__ LP){
  __shared__ alignas(16) char pool[81920];   // K: [0,32768) 2 slots; V: [32768,81920) 3 slots

  const int pr  = blockIdx.x;            // 0..15
  const int h   = blockIdx.y;
  const int s   = blockIdx.z;
  const int kvh = h >> 2;
  const int tid = threadIdx.x;
  const int w = tid >> 6, l = tid & 63;
  const int q5 = l & 31;
  const int hi = l >> 5;
  const int hi4 = hi * 4;
  const float csc = 0.12751743f;         // (1/sqrt(128)) * log2(e)

  // pre-swizzled per-lane global sources (linear LDS dest), as r10
  const u16* Ksrc[4];
  const u16* Vsrc[4];
#pragma unroll
  for (int i = 0; i < 4; i++){
    int blk = w * 4 + i;
    int row = blk * 4 + (l >> 4);
    int cg  = (l & 15) ^ (row & 15);
    Ksrc[i] = Kgb + (size_t)row * QKVS + kvh * HD + cg * 8;
    int d   = blk * 8 + (l >> 3);
    int cv  = (l & 7) ^ (d & 7);
    Vsrc[i] = VTg + (size_t)(kvh * 128 + d) * SEQN + cv * 8;
  }

  auto issueK = [&](int kb, int kv0){
    char* Ksb = pool + kb * 16384;
#pragma unroll
    for (int i = 0; i < 4; i++)
      gload16(Ksrc[i] + (size_t)kv0 * QKVS, Ksb + (w * 4 + i) * 1024);
  };
  auto issueV = [&](int vs, int kv0){
    char* VTb = pool + 32768 + vs * 16384;
#pragma unroll
    for (int i = 0; i < 4; i++)
      gload16(Vsrc[i] + kv0, VTb + (w * 4 + i) * 1024);
  };

  // segment descriptors (as r10)
  const int qlo = pr, qhi = 31 - pr;
  int nseg, sq[2], st0[2], st1[2], smode[2];   // mode: 0 final, 1 partial0, 2 partial1
  if (s == 0){
    nseg = 2;
    sq[0] = qlo; st0[0] = 0;           st1[0] = 2 * pr + 2;   smode[0] = 0;
    sq[1] = qhi; st0[1] = 0;           st1[1] = 31 - 2 * pr;  smode[1] = 1;
  } else {
    nseg = 1;
    sq[0] = qhi; st0[0] = 31 - 2 * pr; st1[0] = 64 - 2 * pr;  smode[0] = 2;
  }

  for (int sg = 0; sg < nseg; sg++){
    const int qt = sq[sg], t0 = st0[sg], t1 = st1[sg], mode = smode[sg];
    const int qbase = qt * 128 + w * 32;
    const int qa    = qbase + q5;

    // Q fragments (B operand): col = l&31 = q, k = hi*8 + j
    short8 qf[8];
    {
      const u16* qp = Qg + (size_t)(qbase + q5) * QKVS + h * HD + hi * 8;
#pragma unroll
      for (int k0 = 0; k0 < 8; k0++) qf[k0] = *(const short8*)(qp + k0 * 16);
    }

    f32x16 Ov[4] = {};
    float Lrow = 0.f;
    float ms = -1e30f;
    f32x16 SvA[2], SvB[2];

    auto qkPhase = [&](f32x16 (&Sv)[2], int kb){
      char* Ksb = pool + kb * 16384;
#pragma unroll
      for (int r = 0; r < 16; r++){ Sv[0][r] = 0.f; Sv[1][r] = 0.f; }
#pragma unroll
      for (int k0 = 0; k0 < 8; k0++){
#pragma unroll
        for (int nb = 0; nb < 2; nb++){
          int kvr = nb * 32 + q5;
          short8 kf = *(const short8*)(Ksb + kvr * 256 + (((k0 * 2 + hi) ^ (kvr & 15)) << 4));
          Sv[nb] = __builtin_amdgcn_mfma_f32_32x32x16_bf16(kf, qf[k0], Sv[nb], 0, 0, 0);
        }
      }
    };

    auto finPhase = [&](f32x16 (&Sv)[2], int vs, int kv0){
      char* VTb = pool + 32768 + vs * 16384;
      if (kv0 + 63 > qbase){
#pragma unroll
        for (int nb = 0; nb < 2; nb++)
#pragma unroll
          for (int r = 0; r < 16; r++){
            int kva = kv0 + nb * 32 + (r & 3) + 8 * (r >> 2) + hi4;
            if (kva > qa) Sv[nb][r] = -1e30f;
          }
      }
      float tm = -3e38f;
#pragma unroll
      for (int nb = 0; nb < 2; nb++)
#pragma unroll
        for (int r = 0; r < 16; r++) tm = fmaxf(tm, Sv[nb][r]);
      tm = fmaxf(tm, __shfl_xor(tm, 32));
      float tms = tm * csc;
      if (!__all(tms - ms <= 8.f)){
        float nms = fmaxf(ms, tms);
        float al = __builtin_amdgcn_exp2f(ms - nms);
        ms = nms;
        Lrow *= al;
#pragma unroll
        for (int nb = 0; nb < 4; nb++)
#pragma unroll
          for (int r = 0; r < 16; r++) Ov[nb][r] *= al;
      }
      float ts = 0.f;
#pragma unroll
      for (int nb = 0; nb < 2; nb++)
#pragma unroll
        for (int r = 0; r < 16; r++){
          float p = __builtin_amdgcn_exp2f(__builtin_fmaf(Sv[nb][r], csc, -ms));
          Sv[nb][r] = p;
          ts += p;
        }
      ts += __shfl_xor(ts, 32);
      Lrow += ts;
#pragma unroll
      for (int kc = 0; kc < 4; kc++){
        const int nb = kc >> 1, rb = (kc & 1) * 8;
        u32 Aw = pk2(Sv[nb][rb + 0], Sv[nb][rb + 1]);
        u32 Bw = pk2(Sv[nb][rb + 2], Sv[nb][rb + 3]);
        u32 Cw = pk2(Sv[nb][rb + 4], Sv[nb][rb + 5]);
        u32 Dw = pk2(Sv[nb][rb + 6], Sv[nb][rb + 7]);
        u32 sAw = __shfl_xor(Aw, 32);
        u32 sBw = __shfl_xor(Bw, 32);
        u32 sCw = __shfl_xor(Cw, 32);
        u32 sDw = __shfl_xor(Dw, 32);
        u32 w0 = hi ? sCw : Aw;
        u32 w1 = hi ? sDw : Bw;
        u32 w2 = hi ? Cw : sAw;
        u32 w3 = hi ? Dw : sBw;
        u32x4 pw4 = {w0, w1, w2, w3};
        short8 pf = *(short8*)&pw4;
#pragma unroll
        for (int nbd = 0; nbd < 4; nbd++){
          int drow = nbd * 32 + q5;
          short8 vf = *(const short8*)(VTb + drow * 128 + (((kc * 2 + hi) ^ (drow & 7)) << 4));
          Ov[nbd] = __builtin_amdgcn_mfma_f32_32x32x16_bf16(vf, pf, Ov[nbd], 0, 0, 0);
        }
      }
    };

    // ---- pipelined main loop: QK(t) overlaps finish(t-1); 1 barrier/tile ----
    __syncthreads();                 // prior segment's pool reads done
    issueK(0, t0 * 64); issueV(0, t0 * 64);
    __syncthreads();                 // prologue tile landed

    for (int t = t0; t < t1; t += 2){
      {   // even step: cur = A
        int kb = (t - t0) & 1;
        if (t + 1 < t1){ issueK(kb ^ 1, (t + 1) * 64); issueV((t + 1 - t0) % 3, (t + 1) * 64); }
        if (t * 64 <= qbase + 31) qkPhase(SvA, kb);
        if (t - 1 >= t0 && (t - 1) * 64 <= qbase + 31) finPhase(SvB, (t - 1 - t0) % 3, (t - 1) * 64);
        __syncthreads();
      }
      if (t + 1 < t1){   // odd step: cur = B
        int kb = (t + 1 - t0) & 1;
        if (t + 2 < t1){ issueK(kb ^ 1, (t + 2) * 64); issueV((t + 2 - t0) % 3, (t + 2) * 64); }
        if ((t + 1) * 64 <= qbase + 31) qkPhase(SvB, kb);
        if (t * 64 <= qbase + 31) finPhase(SvA, (t - t0) % 3, t * 64);
        __syncthreads();
      }
    }
    {   // drain: finish last tile
      int tl = t1 - 1;
      if (tl * 64 <= qbase + 31){
        if ((tl - t0) & 1) finPhase(SvB, (tl - t0) % 3, tl * 64);
        else               finPhase(SvA, (tl - t0) % 3, tl * 64);
      }
    }
    __syncthreads();                 // all finPhase V-reads done before Ew overwrites pool

    // ---- epilogue: (maybe) normalize, transpose via per-wave LDS, store ----
    u16* Ew = (u16*)(pool + w * 8704);     // [32 q][136 d]
    float rl = (mode == 0) ? (1.f / Lrow) : 1.f;
#pragma unroll
    for (int nbd = 0; nbd < 4; nbd++)
#pragma unroll
      for (int r = 0; r < 16; r += 2){
        int d = nbd * 32 + (r & 3) + 8 * (r >> 2) + hi4;
        u32 wpk = pk2(Ov[nbd][r] * rl, Ov[nbd][r + 1] * rl);
        *(u32*)((char*)Ew + q5 * 272 + d * 2) = wpk;
      }
    if (mode == 0){
#pragma unroll
      for (int pass = 0; pass < 8; pass++){
        int q2 = pass * 4 + (l >> 4);
        short8 ov = *(const short8*)((char*)Ew + q2 * 272 + (l & 15) * 16);
        *(short8*)(Aout + (size_t)(qbase + q2) * QDIM + h * HD + (l & 15) * 8) = ov;
      }
    } else {
      const int p = mode - 1;
      u16* dstb = PO + ((size_t)((p * 16 + pr) * NH + h) * 128) * 128;
#pragma unroll
      for (int pass = 0; pass < 8; pass++){
        int q2 = pass * 4 + (l >> 4);
        short8 ov = *(const short8*)((char*)Ew + q2 * 272 + (l & 15) * 16);
        *(short8*)(dstb + (size_t)(w * 32 + q2) * 128 + (l & 15) * 8) = ov;
      }
      if (hi == 0){
        int idx = ((p * 16 + pr) * NH + h) * 128 + w * 32 + q5;
        mP[idx] = ms;
        LP[idx] = Lrow;
      }
    }
  }
}

// ---------------- combine partials for qt_hi = 31 - pr ----------------
__global__ __launch_bounds__(256) void combine_kernel(const u16* __restrict__ PO, const float* __restrict__ mP,
                                                      const float* __restrict__ LP, u16* __restrict__ Aout){
  const int pr = blockIdx.x;
  const int h  = blockIdx.y;
  const int tid = threadIdx.x;
  const int r  = tid >> 1;             // 0..127
  const int dh = (tid & 1) * 64;
  const int qhi = 31 - pr;
  const int idx0 = ((0 * 16 + pr) * NH + h) * 128 + r;
  const int idx1 = ((1 * 16 + pr) * NH + h) * 128 + r;
  float m0 = mP[idx0], m1 = mP[idx1];
  float L0 = LP[idx0], L1 = LP[idx1];
  float M = fmaxf(m0, m1);
  float a0 = __builtin_amdgcn_exp2f(m0 - M);
  float a1 = __builtin_amdgcn_exp2f(m1 - M);
  float rl = 1.f / (L0 * a0 + L1 * a1);
  const u16* o0 = PO + (size_t)idx0 * 128 + dh;
  const u16* o1 = PO + (size_t)idx1 * 128 + dh;
  u16* dst = Aout + (size_t)(qhi * 128 + r) * QDIM + h * HD + dh;
#pragma unroll
  for (int ch = 0; ch < 8; ch++){
    short8 v0 = *(const short8*)(o0 + ch * 8);
    short8 v1 = *(const short8*)(o1 + ch * 8);
    short8 ov;
#pragma unroll
    for (int j = 0; j < 8; j++)
      ov[j] = (short)f2bf((bf2f((u16)v0[j]) * a0 + bf2f((u16)v1[j]) * a1) * rl);
    *(short8*)(dst + ch * 8) = ov;
  }
}

extern "C" void kernel_launch(void* const* d_in, const int* in_sizes, int n_in,
                              void* d_out, int out_size, void* d_ws, size_t ws_size,
                              hipStream_t stream){
  const float* x  = (const float*)d_in[0];
  const float* Wq = (const float*)d_in[1];
  const float* Wk = (const float*)d_in[2];
  const float* Wv = (const float*)d_in[3];
  const float* Wo = (const float*)d_in[4];

  char* p = (char*)d_ws;
  u16* xb    = (u16*)p; p += (size_t)SEQN * HID * 2;
  u16* Wqkvb = (u16*)p; p += (size_t)QKVS * HID * 2;
  u16* Wob   = (u16*)p; p += (size_t)HID * QDIM * 2;
  u16* QKVb  = (u16*)p; p += (size_t)SEQN * QKVS * 2;
  u16* Ab    = (u16*)p; p += (size_t)SEQN * QDIM * 2;
  u16* VTg   = (u16*)p; p += (size_t)SEQN * KVD * 2;
  u16* PO    = (u16*)p; p += (size_t)2 * 16 * NH * 128 * 128 * 2;   // 16 MB
  float* mP  = (float*)p; p += (size_t)2 * 16 * NH * 128 * 4;
  float* LP  = (float*)p; p += (size_t)2 * 16 * NH * 128 * 4;

  const int totg = G1 + G2 + G3 + G4 + G5;
  cvt5_kernel<<<(totg + 255) / 256, 256, 0, stream>>>(x, Wq, Wk, Wv, Wo, xb, Wqkvb, Wob);

  gemm_kernel<0><<<dim3(SEQN/128, QKVS/128), 256, 0, stream>>>(xb, Wqkvb, QKVb, SEQN, QKVS, HID, QKVS);

  rope2_kernel<<<(SEQN*(NH+NKV)*64 + 255) / 256, 256, 0, stream>>>(QKVb);

  vtrans_kernel<<<dim3(SEQN/64, KVD/64), 256, 0, stream>>>(QKVb + QDIM + KVD, QKVS, VTg);

  attn_kernel<<<dim3(16, NH, 2), 256, 0, stream>>>(QKVb, QKVb + QDIM, VTg, Ab, PO, mP, LP);
  combine_kernel<<<dim3(16, NH), 256, 0, stream>>>(PO, mP, LP, Ab);

  gemm_kernel<1><<<dim3(SEQN/128, HID/128), 256, 0, stream>>>(Ab, Wob, d_out, SEQN, HID, QDIM, HID);
}

// Round 12
// 257.509 us; speedup vs baseline: 1.5838x; 1.0334x over previous
//
#include <hip/hip_runtime.h>
#include <hip/hip_bf16.h>

typedef unsigned short u16;
typedef unsigned int u32;
typedef short short8 __attribute__((ext_vector_type(8)));
typedef unsigned short ushort4v __attribute__((ext_vector_type(4)));
typedef float f32x4 __attribute__((ext_vector_type(4)));
typedef float f32x16 __attribute__((ext_vector_type(16)));
typedef u32 u32x4 __attribute__((ext_vector_type(4)));

#define SEQN 4096
#define HID 2048
#define NH 16
#define NKV 4
#define HD 128
#define QDIM 2048   // NH*HD
#define KVD 512     // NKV*HD
#define QKVS 3072   // fused QKV row stride

static __device__ __forceinline__ float bf2f(u16 u){
  unsigned x = ((unsigned)u) << 16; float f; __builtin_memcpy(&f, &x, 4); return f;
}
static __device__ __forceinline__ u16 f2bf(float f){
  unsigned x; __builtin_memcpy(&x, &f, 4);
  x += 0x7fffu + ((x >> 16) & 1u);
  return (u16)(x >> 16);
}
static __device__ __forceinline__ u32 pk2(float a, float b){
  return (u32)f2bf(a) | ((u32)f2bf(b) << 16);
}

// ---------------- fused fp32 -> bf16 convert (all 5 inputs, one launch) ----------------
#define G1 (SEQN*HID/4)
#define G2 (QDIM*HID/4)
#define G3 (KVD*HID/4)
#define G4 (KVD*HID/4)
#define G5 (HID*QDIM/4)
__global__ __launch_bounds__(256) void cvt5_kernel(const float* __restrict__ x,  const float* __restrict__ Wq,
                                                   const float* __restrict__ Wk, const float* __restrict__ Wv,
                                                   const float* __restrict__ Wo, u16* __restrict__ xb,
                                                   u16* __restrict__ Wqkvb, u16* __restrict__ Wob){
  int g = blockIdx.x * 256 + threadIdx.x;
  const float* src; u16* dst; int off;
  if (g < G1)                { src = x;  dst = xb;    off = g; }
  else if (g < G1+G2)        { src = Wq; dst = Wqkvb; off = g - G1; }
  else if (g < G1+G2+G3)     { src = Wk; dst = Wqkvb + (size_t)QDIM*HID;        off = g - (G1+G2); }
  else if (g < G1+G2+G3+G4)  { src = Wv; dst = Wqkvb + (size_t)(QDIM+KVD)*HID;  off = g - (G1+G2+G3); }
  else if (g < G1+G2+G3+G4+G5){ src = Wo; dst = Wob;  off = g - (G1+G2+G3+G4); }
  else return;
  f32x4 v = ((const f32x4*)src)[off];
  ushort4v o;
  o.x = f2bf(v.x); o.y = f2bf(v.y); o.z = f2bf(v.z); o.w = f2bf(v.w);
  ((ushort4v*)dst)[off] = o;
}

// ---------------- RoPE (Q and K in one launch, 4 pairs/thread, strided QKV rows) ----------------
__global__ __launch_bounds__(256) void rope2_kernel(u16* __restrict__ QKVb){
  int idx = blockIdx.x * 256 + threadIdx.x;            // one thread = 8 elems (4 pairs)
  if (idx >= SEQN * (NH + NKV) * 16) return;
  int i8 = idx & 15;                                   // 8-elem chunk within head
  int rest = idx >> 4;
  int h = rest % (NH + NKV);
  int s = rest / (NH + NKV);
  int col = (h < NH) ? h * HD : QDIM + (h - NH) * HD;
  u16* p = QKVb + (size_t)s * QKVS + col + i8 * 8;
  short8 v = *(const short8*)p;
  short8 o;
#pragma unroll
  for (int j = 0; j < 4; j++){
    int i = i8 * 4 + j;                                // pair index 0..63
    float freq = expf(-0.14391156831212788f * (float)i);
    float ang = (float)s * freq;
    float c = cosf(ang), sn = sinf(ang);
    float x1 = bf2f((u16)v[2*j]), x2 = bf2f((u16)v[2*j+1]);
    o[2*j]   = (short)f2bf(x1 * c - x2 * sn);
    o[2*j+1] = (short)f2bf(x1 * sn + x2 * c);
  }
  *(short8*)p = o;
}

// ---------------- V transpose: V[s][c] (strided) -> VTg[c][s] ----------------
__global__ __launch_bounds__(256) void vtrans_kernel(const u16* __restrict__ V, int vstride, u16* __restrict__ VTg){
  __shared__ u16 T[64][72];
  const int s0 = blockIdx.x * 64;
  const int c0 = blockIdx.y * 64;
  const int tid = threadIdx.x;
  const int sl = tid & 63, ch = tid >> 6;
  const u16* src = V + (size_t)(s0 + sl) * vstride + c0 + ch * 16;
  *(short8*)&T[sl][ch * 16]     = *(const short8*)(src);
  *(short8*)&T[sl][ch * 16 + 8] = *(const short8*)(src + 8);
  __syncthreads();
#pragma unroll
  for (int it = 0; it < 16; it++){
    int c = it * 4 + ch;
    VTg[(size_t)(c0 + c) * SEQN + s0 + sl] = T[sl][c];
  }
}

// ---------------- async global->LDS 16B ----------------
static __device__ __forceinline__ void gload16(const void* g, void* l){
  __builtin_amdgcn_global_load_lds((const __attribute__((address_space(1))) void*)g,
                                   (__attribute__((address_space(3))) void*)l, 16, 0, 0);
}

// ---------------- GEMM: C[M][N(ldc)] = A[M][K] * B[N][K]^T ----------------
// bf16 output path uses per-wave LDS-transpose epilogue for vectorized short8 stores.
template<int F32OUT>
__global__ __launch_bounds__(256) void gemm_kernel(const u16* __restrict__ A, const u16* __restrict__ B,
                                                   void* __restrict__ Cout, int M, int N, int Kd, int ldc){
  __shared__ alignas(16) u16 sh[8192];          // As = sh[0..4096), Bs = sh[4096..8192)
  u16* As = sh;
  u16* Bs = sh + 4096;
  const int tid = threadIdx.x;
  const int w = tid >> 6, l = tid & 63;
  const int wr = w >> 1, wc = w & 1;
  const int lc = l & 15, lg = l >> 4;
  const int tm = blockIdx.x * 128, tn = blockIdx.y * 128;

  const int srow = w * 32 + (l >> 2);
  const int scol = (l & 3) * 8;
  const u16* Ag = A + (size_t)(tm + srow) * Kd + scol;
  const u16* Bg = B + (size_t)(tn + srow) * Kd + scol;
  u16* As0 = As + (w * 2) * 512;
  u16* Bs0 = Bs + (w * 2) * 512;

  f32x4 acc[4][4] = {};

  for (int k0 = 0; k0 < Kd; k0 += 32){
    gload16(Ag + k0,                    As0);
    gload16(Ag + k0 + (size_t)16 * Kd,  As0 + 512);
    gload16(Bg + k0,                    Bs0);
    gload16(Bg + k0 + (size_t)16 * Kd,  Bs0 + 512);
    __syncthreads();
    short8 a[4], b[4];
#pragma unroll
    for (int mi = 0; mi < 4; mi++) a[mi] = *(const short8*)&As[(wr*64 + mi*16 + lc) * 32 + lg*8];
#pragma unroll
    for (int ni = 0; ni < 4; ni++) b[ni] = *(const short8*)&Bs[(wc*64 + ni*16 + lc) * 32 + lg*8];
#pragma unroll
    for (int mi = 0; mi < 4; mi++)
#pragma unroll
      for (int ni = 0; ni < 4; ni++)
        acc[mi][ni] = __builtin_amdgcn_mfma_f32_16x16x32_bf16(a[mi], b[ni], acc[mi][ni], 0, 0, 0);
    __syncthreads();
  }

  if (F32OUT){
    // f32 stores: 16 consecutive lanes write 64B contiguous — already granule-efficient
#pragma unroll
    for (int mi = 0; mi < 4; mi++)
#pragma unroll
      for (int ni = 0; ni < 4; ni++)
#pragma unroll
        for (int r = 0; r < 4; r++){
          int row = tm + wr*64 + mi*16 + lg*4 + r;
          int col = tn + wc*64 + ni*16 + lc;
          ((float*)Cout)[(size_t)row * ldc + col] = acc[mi][ni][r];
        }
  } else {
    // bf16: per-wave LDS transpose -> short8 stores (128B per 8 lanes)
    __syncthreads();                       // staging LDS reads done; safe to reuse
    u16* Ew = sh + w * 1168;               // [16][73] u16 per wave (1168 <= 2048)
#pragma unroll
    for (int mi = 0; mi < 4; mi++){
#pragma unroll
      for (int ni = 0; ni < 4; ni++)
#pragma unroll
        for (int r = 0; r < 4; r++)
          Ew[(lg * 4 + r) * 73 + ni * 16 + lc] = f2bf(acc[mi][ni][r]);
      // same-wave write->read: compiler inserts lgkmcnt wait
#pragma unroll
      for (int pass = 0; pass < 2; pass++){
        int row = pass * 8 + (l >> 3);
        short8 v;
#pragma unroll
        for (int j = 0; j < 8; j++) v[j] = (short)Ew[row * 73 + (l & 7) * 8 + j];
        *(short8*)((u16*)Cout + (size_t)(tm + wr*64 + mi*16 + row) * ldc + tn + wc*64 + (l & 7) * 8) = v;
      }
    }
  }
}

// ---------------- Flash attention (causal, GQA), KV-split uniform blocks (r10) ----------------
__global__ __launch_bounds__(256, 2) void attn_kernel(const u16* __restrict__ Qg, const u16* __restrict__ Kgb,
                                                      const u16* __restrict__ VTg, u16* __restrict__ Aout,
                                                      u16* __restrict__ PO, float* __restrict__ mP,
                                                      float* __restrict__ LP){
  __shared__ alignas(16) char pool[65536];   // 2 x (Ks 16KB + VT 16KB)

  const int pr  = blockIdx.x;            // 0..15
  const int h   = blockIdx.y;
  const int s   = blockIdx.z;
  const int kvh = h >> 2;
  const int tid = threadIdx.x;
  const int w = tid >> 6, l = tid & 63;
  const int q5 = l & 31;
  const int hi = l >> 5;
  const int hi4 = hi * 4;
  const float csc = 0.12751743f;         // (1/sqrt(128)) * log2(e)

  const u16* Ksrc[4];
  const u16* Vsrc[4];
#pragma unroll
  for (int i = 0; i < 4; i++){
    int blk = w * 4 + i;
    int row = blk * 4 + (l >> 4);
    int cg  = (l & 15) ^ (row & 15);
    Ksrc[i] = Kgb + (size_t)row * QKVS + kvh * HD + cg * 8;
    int d   = blk * 8 + (l >> 3);
    int cv  = (l & 7) ^ (d & 7);
    Vsrc[i] = VTg + (size_t)(kvh * 128 + d) * SEQN + cv * 8;
  }

  auto issueTile = [&](int b, int kv0){
    char* Ksb = pool + b * 32768;
    char* VTb = Ksb + 16384;
#pragma unroll
    for (int i = 0; i < 4; i++)
      gload16(Ksrc[i] + (size_t)kv0 * QKVS, Ksb + (w * 4 + i) * 1024);
#pragma unroll
    for (int i = 0; i < 4; i++)
      gload16(Vsrc[i] + kv0, VTb + (w * 4 + i) * 1024);
  };

  const int qlo = pr, qhi = 31 - pr;
  int nseg, sq[2], st0[2], st1[2], smode[2];   // mode: 0 final, 1 partial0, 2 partial1
  if (s == 0){
    nseg = 2;
    sq[0] = qlo; st0[0] = 0;           st1[0] = 2 * pr + 2;   smode[0] = 0;
    sq[1] = qhi; st0[1] = 0;           st1[1] = 31 - 2 * pr;  smode[1] = 1;
  } else {
    nseg = 1;
    sq[0] = qhi; st0[0] = 31 - 2 * pr; st1[0] = 64 - 2 * pr;  smode[0] = 2;
  }

  for (int sg = 0; sg < nseg; sg++){
    const int qt = sq[sg], t0 = st0[sg], t1 = st1[sg], mode = smode[sg];
    const int qbase = qt * 128 + w * 32;
    const int qa    = qbase + q5;

    short8 qf[8];
    {
      const u16* qp = Qg + (size_t)(qbase + q5) * QKVS + h * HD + hi * 8;
#pragma unroll
      for (int k0 = 0; k0 < 8; k0++) qf[k0] = *(const short8*)(qp + k0 * 16);
    }

    f32x16 Ov[4] = {};
    float Lrow = 0.f;
    float ms = -1e30f;

    auto computeTile = [&](int b, int kv0){
      if (kv0 > qbase + 31) return;
      char* Ksb = pool + b * 32768;
      char* VTb = Ksb + 16384;
      f32x16 Sv[2] = {};
#pragma unroll
      for (int k0 = 0; k0 < 8; k0++){
#pragma unroll
        for (int nb = 0; nb < 2; nb++){
          int kvr = nb * 32 + q5;
          short8 kf = *(const short8*)(Ksb + kvr * 256 + (((k0 * 2 + hi) ^ (kvr & 15)) << 4));
          Sv[nb] = __builtin_amdgcn_mfma_f32_32x32x16_bf16(kf, qf[k0], Sv[nb], 0, 0, 0);
        }
      }
      if (kv0 + 63 > qbase){
#pragma unroll
        for (int nb = 0; nb < 2; nb++)
#pragma unroll
          for (int r = 0; r < 16; r++){
            int kva = kv0 + nb * 32 + (r & 3) + 8 * (r >> 2) + hi4;
            if (kva > qa) Sv[nb][r] = -1e30f;
          }
      }
      float tm = -3e38f;
#pragma unroll
      for (int nb = 0; nb < 2; nb++)
#pragma unroll
        for (int r = 0; r < 16; r++) tm = fmaxf(tm, Sv[nb][r]);
      tm = fmaxf(tm, __shfl_xor(tm, 32));
      float tms = tm * csc;
      if (!__all(tms - ms <= 8.f)){
        float nms = fmaxf(ms, tms);
        float al = __builtin_amdgcn_exp2f(ms - nms);
        ms = nms;
        Lrow *= al;
#pragma unroll
        for (int nb = 0; nb < 4; nb++)
#pragma unroll
          for (int r = 0; r < 16; r++) Ov[nb][r] *= al;
      }
      float ts = 0.f;
#pragma unroll
      for (int nb = 0; nb < 2; nb++)
#pragma unroll
        for (int r = 0; r < 16; r++){
          float p = __builtin_amdgcn_exp2f(__builtin_fmaf(Sv[nb][r], csc, -ms));
          Sv[nb][r] = p;
          ts += p;
        }
      ts += __shfl_xor(ts, 32);
      Lrow += ts;
#pragma unroll
      for (int kc = 0; kc < 4; kc++){
        const int nb = kc >> 1, rb = (kc & 1) * 8;
        u32 Aw = pk2(Sv[nb][rb + 0], Sv[nb][rb + 1]);
        u32 Bw = pk2(Sv[nb][rb + 2], Sv[nb][rb + 3]);
        u32 Cw = pk2(Sv[nb][rb + 4], Sv[nb][rb + 5]);
        u32 Dw = pk2(Sv[nb][rb + 6], Sv[nb][rb + 7]);
        u32 sAw = __shfl_xor(Aw, 32);
        u32 sBw = __shfl_xor(Bw, 32);
        u32 sCw = __shfl_xor(Cw, 32);
        u32 sDw = __shfl_xor(Dw, 32);
        u32 w0 = hi ? sCw : Aw;
        u32 w1 = hi ? sDw : Bw;
        u32 w2 = hi ? Cw : sAw;
        u32 w3 = hi ? Dw : sBw;
        u32x4 pw4 = {w0, w1, w2, w3};
        short8 pf = *(short8*)&pw4;
#pragma unroll
        for (int nbd = 0; nbd < 4; nbd++){
          int drow = nbd * 32 + q5;
          short8 vf = *(const short8*)(VTb + drow * 128 + (((kc * 2 + hi) ^ (drow & 7)) << 4));
          Ov[nbd] = __builtin_amdgcn_mfma_f32_32x32x16_bf16(vf, pf, Ov[nbd], 0, 0, 0);
        }
      }
    };

    __syncthreads();                 // prior segment's pool reads done
    issueTile(0, t0 * 64);
    __syncthreads();                 // buf0 landed
    int cur = 0;
    for (int t = t0; t < t1; t++){
      if (t + 1 < t1) issueTile(cur ^ 1, (t + 1) * 64);
      computeTile(cur, t * 64);
      __syncthreads();
      cur ^= 1;
    }

    u16* Ew = (u16*)(pool + w * 8704);     // [32 q][136 d]
    float rl = (mode == 0) ? (1.f / Lrow) : 1.f;
#pragma unroll
    for (int nbd = 0; nbd < 4; nbd++)
#pragma unroll
      for (int r = 0; r < 16; r += 2){
        int d = nbd * 32 + (r & 3) + 8 * (r >> 2) + hi4;
        u32 wpk = pk2(Ov[nbd][r] * rl, Ov[nbd][r + 1] * rl);
        *(u32*)((char*)Ew + q5 * 272 + d * 2) = wpk;
      }
    if (mode == 0){
#pragma unroll
      for (int pass = 0; pass < 8; pass++){
        int q2 = pass * 4 + (l >> 4);
        short8 ov = *(const short8*)((char*)Ew + q2 * 272 + (l & 15) * 16);
        *(short8*)(Aout + (size_t)(qbase + q2) * QDIM + h * HD + (l & 15) * 8) = ov;
      }
    } else {
      const int p = mode - 1;
      u16* dstb = PO + ((size_t)((p * 16 + pr) * NH + h) * 128) * 128;
#pragma unroll
      for (int pass = 0; pass < 8; pass++){
        int q2 = pass * 4 + (l >> 4);
        short8 ov = *(const short8*)((char*)Ew + q2 * 272 + (l & 15) * 16);
        *(short8*)(dstb + (size_t)(w * 32 + q2) * 128 + (l & 15) * 8) = ov;
      }
      if (hi == 0){
        int idx = ((p * 16 + pr) * NH + h) * 128 + w * 32 + q5;
        mP[idx] = ms;
        LP[idx] = Lrow;
      }
    }
  }
}

// ---------------- combine partials for qt_hi = 31 - pr ----------------
__global__ __launch_bounds__(256) void combine_kernel(const u16* __restrict__ PO, const float* __restrict__ mP,
                                                      const float* __restrict__ LP, u16* __restrict__ Aout){
  const int pr = blockIdx.x;
  const int h  = blockIdx.y;
  const int tid = threadIdx.x;
  const int r  = tid >> 1;             // 0..127
  const int dh = (tid & 1) * 64;
  const int qhi = 31 - pr;
  const int idx0 = ((0 * 16 + pr) * NH + h) * 128 + r;
  const int idx1 = ((1 * 16 + pr) * NH + h) * 128 + r;
  float m0 = mP[idx0], m1 = mP[idx1];
  float L0 = LP[idx0], L1 = LP[idx1];
  float M = fmaxf(m0, m1);
  float a0 = __builtin_amdgcn_exp2f(m0 - M);
  float a1 = __builtin_amdgcn_exp2f(m1 - M);
  float rl = 1.f / (L0 * a0 + L1 * a1);
  const u16* o0 = PO + (size_t)idx0 * 128 + dh;
  const u16* o1 = PO + (size_t)idx1 * 128 + dh;
  u16* dst = Aout + (size_t)(qhi * 128 + r) * QDIM + h * HD + dh;
#pragma unroll
  for (int ch = 0; ch < 8; ch++){
    short8 v0 = *(const short8*)(o0 + ch * 8);
    short8 v1 = *(const short8*)(o1 + ch * 8);
    short8 ov;
#pragma unroll
    for (int j = 0; j < 8; j++)
      ov[j] = (short)f2bf((bf2f((u16)v0[j]) * a0 + bf2f((u16)v1[j]) * a1) * rl);
    *(short8*)(dst + ch * 8) = ov;
  }
}

extern "C" void kernel_launch(void* const* d_in, const int* in_sizes, int n_in,
                              void* d_out, int out_size, void* d_ws, size_t ws_size,
                              hipStream_t stream){
  const float* x  = (const float*)d_in[0];
  const float* Wq = (const float*)d_in[1];
  const float* Wk = (const float*)d_in[2];
  const float* Wv = (const float*)d_in[3];
  const float* Wo = (const float*)d_in[4];

  char* p = (char*)d_ws;
  u16* xb    = (u16*)p; p += (size_t)SEQN * HID * 2;
  u16* Wqkvb = (u16*)p; p += (size_t)QKVS * HID * 2;
  u16* Wob   = (u16*)p; p += (size_t)HID * QDIM * 2;
  u16* QKVb  = (u16*)p; p += (size_t)SEQN * QKVS * 2;
  u16* Ab    = (u16*)p; p += (size_t)SEQN * QDIM * 2;
  u16* VTg   = (u16*)p; p += (size_t)SEQN * KVD * 2;
  u16* PO    = (u16*)p; p += (size_t)2 * 16 * NH * 128 * 128 * 2;   // 16 MB
  float* mP  = (float*)p; p += (size_t)2 * 16 * NH * 128 * 4;
  float* LP  = (float*)p; p += (size_t)2 * 16 * NH * 128 * 4;

  const int totg = G1 + G2 + G3 + G4 + G5;
  cvt5_kernel<<<(totg + 255) / 256, 256, 0, stream>>>(x, Wq, Wk, Wv, Wo, xb, Wqkvb, Wob);

  gemm_kernel<0><<<dim3(SEQN/128, QKVS/128), 256, 0, stream>>>(xb, Wqkvb, QKVb, SEQN, QKVS, HID, QKVS);

  rope2_kernel<<<(SEQN*(NH+NKV)*16 + 255) / 256, 256, 0, stream>>>(QKVb);

  vtrans_kernel<<<dim3(SEQN/64, KVD/64), 256, 0, stream>>>(QKVb + QDIM + KVD, QKVS, VTg);

  attn_kernel<<<dim3(16, NH, 2), 256, 0, stream>>>(QKVb, QKVb + QDIM, VTg, Ab, PO, mP, LP);
  combine_kernel<<<dim3(16, NH), 256, 0, stream>>>(PO, mP, LP, Ab);

  gemm_kernel<1><<<dim3(SEQN/128, HID/128), 256, 0, stream>>>(Ab, Wob, d_out, SEQN, HID, QDIM, HID);
}

// Round 13
// 254.443 us; speedup vs baseline: 1.6029x; 1.0121x over previous
//
#include <hip/hip_runtime.h>
#include <hip/hip_bf16.h>

typedef unsigned short u16;
typedef unsigned int u32;
typedef short short8 __attribute__((ext_vector_type(8)));
typedef unsigned short ushort4v __attribute__((ext_vector_type(4)));
typedef float f32x4 __attribute__((ext_vector_type(4)));
typedef float f32x16 __attribute__((ext_vector_type(16)));
typedef u32 u32x4 __attribute__((ext_vector_type(4)));

#define SEQN 4096
#define HID 2048
#define NH 16
#define NKV 4
#define HD 128
#define QDIM 2048   // NH*HD
#define KVD 512     // NKV*HD
#define QKVS 3072   // fused QKV row stride

static __device__ __forceinline__ float bf2f(u16 u){
  unsigned x = ((unsigned)u) << 16; float f; __builtin_memcpy(&f, &x, 4); return f;
}
static __device__ __forceinline__ u16 f2bf(float f){
  unsigned x; __builtin_memcpy(&x, &f, 4);
  x += 0x7fffu + ((x >> 16) & 1u);
  return (u16)(x >> 16);
}
// cheap round-half-up bf16 (<=1 ulp vs RNE)
static __device__ __forceinline__ u16 f2bfc(float f){
  unsigned x; __builtin_memcpy(&x, &f, 4);
  return (u16)((x + 0x8000u) >> 16);
}
// cheap packed pair: low16 = bf16(a), high16 = bf16(b)  (5 inst, exact semantics)
static __device__ __forceinline__ u32 pkr(float a, float b){
  u32 ab, bb; __builtin_memcpy(&ab, &a, 4); __builtin_memcpy(&bb, &b, 4);
  return ((ab + 0x8000u) >> 16) | ((bb + 0x8000u) & 0xffff0000u);
}

// ---------------- fused fp32 -> bf16 convert (all 5 inputs, one launch) ----------------
#define G1 (SEQN*HID/4)
#define G2 (QDIM*HID/4)
#define G3 (KVD*HID/4)
#define G4 (KVD*HID/4)
#define G5 (HID*QDIM/4)
__global__ __launch_bounds__(256) void cvt5_kernel(const float* __restrict__ x,  const float* __restrict__ Wq,
                                                   const float* __restrict__ Wk, const float* __restrict__ Wv,
                                                   const float* __restrict__ Wo, u16* __restrict__ xb,
                                                   u16* __restrict__ Wqkvb, u16* __restrict__ Wob){
  int g = blockIdx.x * 256 + threadIdx.x;
  const float* src; u16* dst; int off;
  if (g < G1)                { src = x;  dst = xb;    off = g; }
  else if (g < G1+G2)        { src = Wq; dst = Wqkvb; off = g - G1; }
  else if (g < G1+G2+G3)     { src = Wk; dst = Wqkvb + (size_t)QDIM*HID;        off = g - (G1+G2); }
  else if (g < G1+G2+G3+G4)  { src = Wv; dst = Wqkvb + (size_t)(QDIM+KVD)*HID;  off = g - (G1+G2+G3); }
  else if (g < G1+G2+G3+G4+G5){ src = Wo; dst = Wob;  off = g - (G1+G2+G3+G4); }
  else return;
  f32x4 v = ((const f32x4*)src)[off];
  ushort4v o;
  o.x = f2bf(v.x); o.y = f2bf(v.y); o.z = f2bf(v.z); o.w = f2bf(v.w);
  ((ushort4v*)dst)[off] = o;
}

// ---------------- fused RoPE (Q,K) + V transpose, one launch ----------------
#define ROPE_BLKS (SEQN * (NH + NKV) * 16 / 256)     // 5120
__global__ __launch_bounds__(256) void prep_kernel(u16* __restrict__ QKVb, u16* __restrict__ VTg){
  __shared__ u16 T[64][72];
  const int bid = blockIdx.x;
  const int tid = threadIdx.x;
  if (bid < ROPE_BLKS){
    int idx = bid * 256 + tid;                 // one thread = 8 elems (4 pairs)
    int i8 = idx & 15;
    int rest = idx >> 4;
    int h = rest % (NH + NKV);
    int s = rest / (NH + NKV);
    int col = (h < NH) ? h * HD : QDIM + (h - NH) * HD;
    u16* p = QKVb + (size_t)s * QKVS + col + i8 * 8;
    short8 v = *(const short8*)p;
    short8 o;
#pragma unroll
    for (int j = 0; j < 4; j++){
      int i = i8 * 4 + j;
      float freq = expf(-0.14391156831212788f * (float)i);
      float ang = (float)s * freq;
      float c = cosf(ang), sn = sinf(ang);
      float x1 = bf2f((u16)v[2*j]), x2 = bf2f((u16)v[2*j+1]);
      o[2*j]   = (short)f2bfc(x1 * c - x2 * sn);
      o[2*j+1] = (short)f2bfc(x1 * sn + x2 * c);
    }
    *(short8*)p = o;
  } else {
    const int b2 = bid - ROPE_BLKS;
    const int s0 = (b2 & 63) * 64;
    const int c0 = (b2 >> 6) * 64;
    const int sl = tid & 63, ch = tid >> 6;
    const u16* src = QKVb + QDIM + KVD + (size_t)(s0 + sl) * QKVS + c0 + ch * 16;
    *(short8*)&T[sl][ch * 16]     = *(const short8*)(src);
    *(short8*)&T[sl][ch * 16 + 8] = *(const short8*)(src + 8);
    __syncthreads();
#pragma unroll
    for (int it = 0; it < 16; it++){
      int c = it * 4 + ch;
      VTg[(size_t)(c0 + c) * SEQN + s0 + sl] = T[sl][c];
    }
  }
}

// ---------------- async global->LDS 16B ----------------
static __device__ __forceinline__ void gload16(const void* g, void* l){
  __builtin_amdgcn_global_load_lds((const __attribute__((address_space(1))) void*)g,
                                   (__attribute__((address_space(3))) void*)l, 16, 0, 0);
}

// ---------------- GEMM: C[M][N(ldc)] = A[M][K] * B[N][K]^T ----------------
template<int F32OUT>
__global__ __launch_bounds__(256) void gemm_kernel(const u16* __restrict__ A, const u16* __restrict__ B,
                                                   void* __restrict__ Cout, int M, int N, int Kd, int ldc){
  __shared__ alignas(16) u16 sh[8192];          // As = sh[0..4096), Bs = sh[4096..8192)
  u16* As = sh;
  u16* Bs = sh + 4096;
  const int tid = threadIdx.x;
  const int w = tid >> 6, l = tid & 63;
  const int wr = w >> 1, wc = w & 1;
  const int lc = l & 15, lg = l >> 4;
  const int tm = blockIdx.x * 128, tn = blockIdx.y * 128;

  const int srow = w * 32 + (l >> 2);
  const int scol = (l & 3) * 8;
  const u16* Ag = A + (size_t)(tm + srow) * Kd + scol;
  const u16* Bg = B + (size_t)(tn + srow) * Kd + scol;
  u16* As0 = As + (w * 2) * 512;
  u16* Bs0 = Bs + (w * 2) * 512;

  f32x4 acc[4][4] = {};

  for (int k0 = 0; k0 < Kd; k0 += 32){
    gload16(Ag + k0,                    As0);
    gload16(Ag + k0 + (size_t)16 * Kd,  As0 + 512);
    gload16(Bg + k0,                    Bs0);
    gload16(Bg + k0 + (size_t)16 * Kd,  Bs0 + 512);
    __syncthreads();
    short8 a[4], b[4];
#pragma unroll
    for (int mi = 0; mi < 4; mi++) a[mi] = *(const short8*)&As[(wr*64 + mi*16 + lc) * 32 + lg*8];
#pragma unroll
    for (int ni = 0; ni < 4; ni++) b[ni] = *(const short8*)&Bs[(wc*64 + ni*16 + lc) * 32 + lg*8];
#pragma unroll
    for (int mi = 0; mi < 4; mi++)
#pragma unroll
      for (int ni = 0; ni < 4; ni++)
        acc[mi][ni] = __builtin_amdgcn_mfma_f32_16x16x32_bf16(a[mi], b[ni], acc[mi][ni], 0, 0, 0);
    __syncthreads();
  }

  if (F32OUT){
#pragma unroll
    for (int mi = 0; mi < 4; mi++)
#pragma unroll
      for (int ni = 0; ni < 4; ni++)
#pragma unroll
        for (int r = 0; r < 4; r++){
          int row = tm + wr*64 + mi*16 + lg*4 + r;
          int col = tn + wc*64 + ni*16 + lc;
          ((float*)Cout)[(size_t)row * ldc + col] = acc[mi][ni][r];
        }
  } else {
    __syncthreads();
    u16* Ew = sh + w * 1168;               // [16][73] u16 per wave
#pragma unroll
    for (int mi = 0; mi < 4; mi++){
#pragma unroll
      for (int ni = 0; ni < 4; ni++)
#pragma unroll
        for (int r = 0; r < 4; r++)
          Ew[(lg * 4 + r) * 73 + ni * 16 + lc] = f2bfc(acc[mi][ni][r]);
#pragma unroll
      for (int pass = 0; pass < 2; pass++){
        int row = pass * 8 + (l >> 3);
        short8 v;
#pragma unroll
        for (int j = 0; j < 8; j++) v[j] = (short)Ew[row * 73 + (l & 7) * 8 + j];
        *(short8*)((u16*)Cout + (size_t)(tm + wr*64 + mi*16 + row) * ldc + tn + wc*64 + (l & 7) * 8) = v;
      }
    }
  }
}

// ---------------- Flash attention (causal, GQA), KV-split uniform blocks ----------------
__global__ __launch_bounds__(256, 2) void attn_kernel(const u16* __restrict__ Qg, const u16* __restrict__ Kgb,
                                                      const u16* __restrict__ VTg, u16* __restrict__ Aout,
                                                      u16* __restrict__ PO, float* __restrict__ mP,
                                                      float* __restrict__ LP){
  __shared__ alignas(16) char pool[65536];   // 2 x (Ks 16KB + VT 16KB)

  const int pr  = blockIdx.x;            // 0..15
  const int h   = blockIdx.y;
  const int s   = blockIdx.z;
  const int kvh = h >> 2;
  const int tid = threadIdx.x;
  const int w = tid >> 6, l = tid & 63;
  const int q5 = l & 31;
  const int hi = l >> 5;
  const int hi4 = hi * 4;
  const float csc = 0.12751743f;         // (1/sqrt(128)) * log2(e)

  const u16* Ksrc[4];
  const u16* Vsrc[4];
#pragma unroll
  for (int i = 0; i < 4; i++){
    int blk = w * 4 + i;
    int row = blk * 4 + (l >> 4);
    int cg  = (l & 15) ^ (row & 15);
    Ksrc[i] = Kgb + (size_t)row * QKVS + kvh * HD + cg * 8;
    int d   = blk * 8 + (l >> 3);
    int cv  = (l & 7) ^ (d & 7);
    Vsrc[i] = VTg + (size_t)(kvh * 128 + d) * SEQN + cv * 8;
  }

  auto issueTile = [&](int b, int kv0){
    char* Ksb = pool + b * 32768;
    char* VTb = Ksb + 16384;
#pragma unroll
    for (int i = 0; i < 4; i++)
      gload16(Ksrc[i] + (size_t)kv0 * QKVS, Ksb + (w * 4 + i) * 1024);
#pragma unroll
    for (int i = 0; i < 4; i++)
      gload16(Vsrc[i] + kv0, VTb + (w * 4 + i) * 1024);
  };

  const int qlo = pr, qhi = 31 - pr;
  int nseg, sq[2], st0[2], st1[2], smode[2];   // mode: 0 final, 1 partial0, 2 partial1
  if (s == 0){
    nseg = 2;
    sq[0] = qlo; st0[0] = 0;           st1[0] = 2 * pr + 2;   smode[0] = 0;
    sq[1] = qhi; st0[1] = 0;           st1[1] = 31 - 2 * pr;  smode[1] = 1;
  } else {
    nseg = 1;
    sq[0] = qhi; st0[0] = 31 - 2 * pr; st1[0] = 64 - 2 * pr;  smode[0] = 2;
  }

  for (int sg = 0; sg < nseg; sg++){
    const int qt = sq[sg], t0 = st0[sg], t1 = st1[sg], mode = smode[sg];
    const int qbase = qt * 128 + w * 32;
    const int qa    = qbase + q5;

    short8 qf[8];
    {
      const u16* qp = Qg + (size_t)(qbase + q5) * QKVS + h * HD + hi * 8;
#pragma unroll
      for (int k0 = 0; k0 < 8; k0++) qf[k0] = *(const short8*)(qp + k0 * 16);
    }

    f32x16 Ov[4] = {};
    float Lrow = 0.f;
    float ms = -1e30f;

    auto computeTile = [&](int b, int kv0){
      if (kv0 > qbase + 31) return;
      char* Ksb = pool + b * 32768;
      char* VTb = Ksb + 16384;
      f32x16 Sv[2] = {};
#pragma unroll
      for (int k0 = 0; k0 < 8; k0++){
#pragma unroll
        for (int nb = 0; nb < 2; nb++){
          int kvr = nb * 32 + q5;
          short8 kf = *(const short8*)(Ksb + kvr * 256 + (((k0 * 2 + hi) ^ (kvr & 15)) << 4));
          Sv[nb] = __builtin_amdgcn_mfma_f32_32x32x16_bf16(kf, qf[k0], Sv[nb], 0, 0, 0);
        }
      }
      if (kv0 + 63 > qbase){
#pragma unroll
        for (int nb = 0; nb < 2; nb++)
#pragma unroll
          for (int r = 0; r < 16; r++){
            int kva = kv0 + nb * 32 + (r & 3) + 8 * (r >> 2) + hi4;
            if (kva > qa) Sv[nb][r] = -1e30f;
          }
      }
      // max via max3-friendly pairs
      float tm = fmaxf(Sv[0][0], Sv[0][1]);
#pragma unroll
      for (int nb = 0; nb < 2; nb++)
#pragma unroll
        for (int r = (nb == 0 ? 2 : 0); r < 16; r += 2)
          tm = fmaxf(tm, fmaxf(Sv[nb][r], Sv[nb][r + 1]));
      tm = fmaxf(tm, __shfl_xor(tm, 32));
      float tms = tm * csc;
      if (!__all(tms - ms <= 8.f)){
        float nms = fmaxf(ms, tms);
        float al = __builtin_amdgcn_exp2f(ms - nms);
        ms = nms;
        Lrow *= al;
#pragma unroll
        for (int nb = 0; nb < 4; nb++)
#pragma unroll
          for (int r = 0; r < 16; r++) Ov[nb][r] *= al;
      }
      float ts0 = 0.f, ts1 = 0.f;
#pragma unroll
      for (int nb = 0; nb < 2; nb++)
#pragma unroll
        for (int r = 0; r < 16; r += 2){
          float p0 = __builtin_amdgcn_exp2f(__builtin_fmaf(Sv[nb][r],     csc, -ms));
          float p1 = __builtin_amdgcn_exp2f(__builtin_fmaf(Sv[nb][r + 1], csc, -ms));
          Sv[nb][r] = p0; Sv[nb][r + 1] = p1;
          ts0 += p0; ts1 += p1;
        }
      float ts = ts0 + ts1;
      ts += __shfl_xor(ts, 32);
      Lrow += ts;
#pragma unroll
      for (int kc = 0; kc < 4; kc++){
        const int nb = kc >> 1, rb = (kc & 1) * 8;
        u32 Aw = pkr(Sv[nb][rb + 0], Sv[nb][rb + 1]);
        u32 Bw = pkr(Sv[nb][rb + 2], Sv[nb][rb + 3]);
        u32 Cw = pkr(Sv[nb][rb + 4], Sv[nb][rb + 5]);
        u32 Dw = pkr(Sv[nb][rb + 6], Sv[nb][rb + 7]);
        u32 sAw = __shfl_xor(Aw, 32);
        u32 sBw = __shfl_xor(Bw, 32);
        u32 sCw = __shfl_xor(Cw, 32);
        u32 sDw = __shfl_xor(Dw, 32);
        u32 w0 = hi ? sCw : Aw;
        u32 w1 = hi ? sDw : Bw;
        u32 w2 = hi ? Cw : sAw;
        u32 w3 = hi ? Dw : sBw;
        u32x4 pw4 = {w0, w1, w2, w3};
        short8 pf = *(short8*)&pw4;
#pragma unroll
        for (int nbd = 0; nbd < 4; nbd++){
          int drow = nbd * 32 + q5;
          short8 vf = *(const short8*)(VTb + drow * 128 + (((kc * 2 + hi) ^ (drow & 7)) << 4));
          Ov[nbd] = __builtin_amdgcn_mfma_f32_32x32x16_bf16(vf, pf, Ov[nbd], 0, 0, 0);
        }
      }
    };

    __syncthreads();                 // prior segment's pool reads done
    issueTile(0, t0 * 64);
    __syncthreads();                 // buf0 landed
    int cur = 0;
    for (int t = t0; t < t1; t++){
      if (t + 1 < t1) issueTile(cur ^ 1, (t + 1) * 64);
      computeTile(cur, t * 64);
      __syncthreads();
      cur ^= 1;
    }

    u16* Ew = (u16*)(pool + w * 8704);     // [32 q][136 d]
    float rl = (mode == 0) ? (1.f / Lrow) : 1.f;
#pragma unroll
    for (int nbd = 0; nbd < 4; nbd++)
#pragma unroll
      for (int r = 0; r < 16; r += 2){
        int d = nbd * 32 + (r & 3) + 8 * (r >> 2) + hi4;
        u32 wpk = pkr(Ov[nbd][r] * rl, Ov[nbd][r + 1] * rl);
        *(u32*)((char*)Ew + q5 * 272 + d * 2) = wpk;
      }
    if (mode == 0){
#pragma unroll
      for (int pass = 0; pass < 8; pass++){
        int q2 = pass * 4 + (l >> 4);
        short8 ov = *(const short8*)((char*)Ew + q2 * 272 + (l & 15) * 16);
        *(short8*)(Aout + (size_t)(qbase + q2) * QDIM + h * HD + (l & 15) * 8) = ov;
      }
    } else {
      const int p = mode - 1;
      u16* dstb = PO + ((size_t)((p * 16 + pr) * NH + h) * 128) * 128;
#pragma unroll
      for (int pass = 0; pass < 8; pass++){
        int q2 = pass * 4 + (l >> 4);
        short8 ov = *(const short8*)((char*)Ew + q2 * 272 + (l & 15) * 16);
        *(short8*)(dstb + (size_t)(w * 32 + q2) * 128 + (l & 15) * 8) = ov;
      }
      if (hi == 0){
        int idx = ((p * 16 + pr) * NH + h) * 128 + w * 32 + q5;
        mP[idx] = ms;
        LP[idx] = Lrow;
      }
    }
  }
}

// ---------------- combine partials for qt_hi = 31 - pr ----------------
__global__ __launch_bounds__(256) void combine_kernel(const u16* __restrict__ PO, const float* __restrict__ mP,
                                                      const float* __restrict__ LP, u16* __restrict__ Aout){
  const int pr = blockIdx.x;
  const int h  = blockIdx.y;
  const int tid = threadIdx.x;
  const int r  = tid >> 1;             // 0..127
  const int dh = (tid & 1) * 64;
  const int qhi = 31 - pr;
  const int idx0 = ((0 * 16 + pr) * NH + h) * 128 + r;
  const int idx1 = ((1 * 16 + pr) * NH + h) * 128 + r;
  float m0 = mP[idx0], m1 = mP[idx1];
  float L0 = LP[idx0], L1 = LP[idx1];
  float M = fmaxf(m0, m1);
  float a0 = __builtin_amdgcn_exp2f(m0 - M);
  float a1 = __builtin_amdgcn_exp2f(m1 - M);
  float rl = 1.f / (L0 * a0 + L1 * a1);
  const u16* o0 = PO + (size_t)idx0 * 128 + dh;
  const u16* o1 = PO + (size_t)idx1 * 128 + dh;
  u16* dst = Aout + (size_t)(qhi * 128 + r) * QDIM + h * HD + dh;
#pragma unroll
  for (int ch = 0; ch < 8; ch++){
    short8 v0 = *(const short8*)(o0 + ch * 8);
    short8 v1 = *(const short8*)(o1 + ch * 8);
    u32x4 ow;
#pragma unroll
    for (int j = 0; j < 4; j++){
      float e0 = (bf2f((u16)v0[2*j])   * a0 + bf2f((u16)v1[2*j])   * a1) * rl;
      float e1 = (bf2f((u16)v0[2*j+1]) * a0 + bf2f((u16)v1[2*j+1]) * a1) * rl;
      ow[j] = pkr(e0, e1);
    }
    *(u32x4*)(dst + ch * 8) = ow;
  }
}

extern "C" void kernel_launch(void* const* d_in, const int* in_sizes, int n_in,
                              void* d_out, int out_size, void* d_ws, size_t ws_size,
                              hipStream_t stream){
  const float* x  = (const float*)d_in[0];
  const float* Wq = (const float*)d_in[1];
  const float* Wk = (const float*)d_in[2];
  const float* Wv = (const float*)d_in[3];
  const float* Wo = (const float*)d_in[4];

  char* p = (char*)d_ws;
  u16* xb    = (u16*)p; p += (size_t)SEQN * HID * 2;
  u16* Wqkvb = (u16*)p; p += (size_t)QKVS * HID * 2;
  u16* Wob   = (u16*)p; p += (size_t)HID * QDIM * 2;
  u16* QKVb  = (u16*)p; p += (size_t)SEQN * QKVS * 2;
  u16* Ab    = (u16*)p; p += (size_t)SEQN * QDIM * 2;
  u16* VTg   = (u16*)p; p += (size_t)SEQN * KVD * 2;
  u16* PO    = (u16*)p; p += (size_t)2 * 16 * NH * 128 * 128 * 2;   // 16 MB
  float* mP  = (float*)p; p += (size_t)2 * 16 * NH * 128 * 4;
  float* LP  = (float*)p; p += (size_t)2 * 16 * NH * 128 * 4;

  const int totg = G1 + G2 + G3 + G4 + G5;
  cvt5_kernel<<<(totg + 255) / 256, 256, 0, stream>>>(x, Wq, Wk, Wv, Wo, xb, Wqkvb, Wob);

  gemm_kernel<0><<<dim3(SEQN/128, QKVS/128), 256, 0, stream>>>(xb, Wqkvb, QKVb, SEQN, QKVS, HID, QKVS);

  prep_kernel<<<ROPE_BLKS + (SEQN/64) * (KVD/64), 256, 0, stream>>>(QKVb, VTg);

  attn_kernel<<<dim3(16, NH, 2), 256, 0, stream>>>(QKVb, QKVb + QDIM, VTg, Ab, PO, mP, LP);
  combine_kernel<<<dim3(16, NH), 256, 0, stream>>>(PO, mP, LP, Ab);

  gemm_kernel<1><<<dim3(SEQN/128, HID/128), 256, 0, stream>>>(Ab, Wob, d_out, SEQN, HID, QDIM, HID);
}